// Round 1
// baseline (944.180 us; speedup 1.0000x reference)
//
#include <hip/hip_runtime.h>

#define F_IN   512
#define HD     64     // H*D layer-1 output width
#define NHEAD  8
#define DIMH   8
#define NC     40     // classes
#define NEG    0.2f

__device__ __forceinline__ float lrelu(float x) { return x > 0.0f ? x : NEG * x; }

// ---------------- CSR build ----------------
__global__ void count_kernel(const int* __restrict__ dst, int* __restrict__ deg, int E) {
    int e = blockIdx.x * 256 + threadIdx.x;
    if (e < E) atomicAdd(&deg[dst[e]], 1);
}

__global__ __launch_bounds__(256) void scanA_kernel(const int* __restrict__ deg,
                                                    int* __restrict__ incl,
                                                    int* __restrict__ bsum, int Nn) {
    __shared__ int wsum[4];
    int t = threadIdx.x, b = blockIdx.x;
    int base = b * 1024 + t * 4;
    int v0 = (base + 0) < Nn ? deg[base + 0] : 0;
    int v1 = (base + 1) < Nn ? deg[base + 1] : 0;
    int v2 = (base + 2) < Nn ? deg[base + 2] : 0;
    int v3 = (base + 3) < Nn ? deg[base + 3] : 0;
    int p0 = v0, p1 = p0 + v1, p2 = p1 + v2, p3 = p2 + v3;
    int lane = t & 63, w = t >> 6;
    int sc = p3;
    for (int off = 1; off < 64; off <<= 1) {
        int u = __shfl_up(sc, off);
        if (lane >= off) sc += u;
    }
    if (lane == 63) wsum[w] = sc;
    __syncthreads();
    int woff = 0;
#pragma unroll
    for (int i = 0; i < 4; ++i) if (i < w) woff += wsum[i];
    int excl = woff + sc - p3;
    if (base + 0 < Nn) incl[base + 0] = excl + p0;
    if (base + 1 < Nn) incl[base + 1] = excl + p1;
    if (base + 2 < Nn) incl[base + 2] = excl + p2;
    if (base + 3 < Nn) incl[base + 3] = excl + p3;
    if (t == 0) bsum[b] = wsum[0] + wsum[1] + wsum[2] + wsum[3];
}

__global__ void scanB_kernel(int* __restrict__ bsum, int nb) {
    int lane = threadIdx.x;  // 64 threads
    int a = lane < nb ? bsum[lane] : 0;
    int c = (lane + 64) < nb ? bsum[lane + 64] : 0;
    int sa = a, sc2 = c;
    for (int off = 1; off < 64; off <<= 1) {
        int u = __shfl_up(sa, off);  if (lane >= off) sa += u;
        int u2 = __shfl_up(sc2, off); if (lane >= off) sc2 += u2;
    }
    int totA = __shfl(sa, 63);
    int ea = sa - a;
    int ec = totA + sc2 - c;
    if (lane < nb) bsum[lane] = ea;
    if (lane + 64 < nb) bsum[lane + 64] = ec;
}

__global__ void scanC_kernel(const int* __restrict__ incl, const int* __restrict__ bsum,
                             const int* __restrict__ deg, int* __restrict__ rp,
                             int* __restrict__ wr, int Nn) {
    int i = blockIdx.x * 256 + threadIdx.x;
    if (i == 0) rp[0] = 0;
    if (i < Nn) {
        int v = incl[i] + bsum[i >> 10];
        rp[i + 1] = v;
        wr[i] = v - deg[i];
    }
}

__global__ void scatter_kernel(const int* __restrict__ src, const int* __restrict__ dst,
                               int* __restrict__ wr, int* __restrict__ col, int E) {
    int e = blockIdx.x * 256 + threadIdx.x;
    if (e < E) {
        int d = dst[e];
        int pos = atomicAdd(&wr[d], 1);
        col[pos] = src[e];
    }
}

// ---------------- GEMM1: h1p = x @ W1   (Nn x 512) * (512 x 64) ----------------
#define BM 64
#define BK 32
__global__ __launch_bounds__(256) void gemm1_kernel(const float* __restrict__ X,
                                                    const float* __restrict__ W,
                                                    float* __restrict__ Hout, int Nn) {
    __shared__ float As[BK][BM + 4];  // transposed: As[k][row]
    __shared__ float Bs[BK][HD + 4];
    int tid = threadIdx.x;
    int row0 = blockIdx.x * BM;
    float acc[4][4] = {{0}};
    int tr = tid / 16, tc = tid % 16;
    for (int k0 = 0; k0 < F_IN; k0 += BK) {
#pragma unroll
        for (int i = 0; i < 2; ++i) {
            int idx = tid + i * 256;   // 0..511
            int r = idx >> 3;
            int kk = (idx & 7) * 4;
            float4 v = make_float4(0, 0, 0, 0);
            int gr = row0 + r;
            if (gr < Nn) v = *reinterpret_cast<const float4*>(&X[(size_t)gr * F_IN + k0 + kk]);
            As[kk + 0][r] = v.x; As[kk + 1][r] = v.y; As[kk + 2][r] = v.z; As[kk + 3][r] = v.w;
        }
#pragma unroll
        for (int i = 0; i < 2; ++i) {
            int idx = tid + i * 256;
            int kk = idx >> 4;          // 0..31
            int c = (idx & 15) * 4;
            float4 v = *reinterpret_cast<const float4*>(&W[(size_t)(k0 + kk) * HD + c]);
            *reinterpret_cast<float4*>(&Bs[kk][c]) = v;
        }
        __syncthreads();
#pragma unroll
        for (int k = 0; k < BK; ++k) {
            float4 a = *reinterpret_cast<const float4*>(&As[k][tr * 4]);
            float4 b = *reinterpret_cast<const float4*>(&Bs[k][tc * 4]);
            acc[0][0] += a.x * b.x; acc[0][1] += a.x * b.y; acc[0][2] += a.x * b.z; acc[0][3] += a.x * b.w;
            acc[1][0] += a.y * b.x; acc[1][1] += a.y * b.y; acc[1][2] += a.y * b.z; acc[1][3] += a.y * b.w;
            acc[2][0] += a.z * b.x; acc[2][1] += a.z * b.y; acc[2][2] += a.z * b.z; acc[2][3] += a.z * b.w;
            acc[3][0] += a.w * b.x; acc[3][1] += a.w * b.y; acc[3][2] += a.w * b.z; acc[3][3] += a.w * b.w;
        }
        __syncthreads();
    }
#pragma unroll
    for (int i = 0; i < 4; ++i) {
        int gr = row0 + tr * 4 + i;
        if (gr < Nn) {
            float4 v = make_float4(acc[i][0], acc[i][1], acc[i][2], acc[i][3]);
            *reinterpret_cast<float4*>(&Hout[(size_t)gr * HD + tc * 4]) = v;
        }
    }
}

// ---------------- alpha1: per-node per-head attention logits ----------------
__global__ void alpha1_kernel(const float* __restrict__ Hp, const float* __restrict__ att_s,
                              const float* __restrict__ att_d, float* __restrict__ as_o,
                              float* __restrict__ ad_o, int Nn) {
    int n = blockIdx.x * 4 + (threadIdx.x >> 6);
    int lane = threadIdx.x & 63;
    if (n >= Nn) return;
    float h = Hp[(size_t)n * HD + lane];
    float s = h * att_s[lane];
    float d = h * att_d[lane];
#pragma unroll
    for (int m = 1; m < 8; m <<= 1) { s += __shfl_xor(s, m); d += __shfl_xor(d, m); }
    if ((lane & 7) == 0) {
        as_o[n * NHEAD + (lane >> 3)] = s;
        ad_o[n * NHEAD + (lane >> 3)] = d;
    }
}

// ---------------- agg1: edge softmax + aggregate, + bias + ELU ----------------
__global__ __launch_bounds__(256) void agg1_kernel(const float* __restrict__ Hp,
                                                   const float* __restrict__ as1,
                                                   const float* __restrict__ ad1,
                                                   const int* __restrict__ rp,
                                                   const int* __restrict__ col,
                                                   const float* __restrict__ b1,
                                                   float* __restrict__ H1out, int Nn) {
    int n = blockIdx.x * 4 + (threadIdx.x >> 6);
    int lane = threadIdx.x & 63;
    if (n >= Nn) return;
    int h = lane >> 3;
    int beg = rp[n], end = rp[n + 1];
    float ad = ad1[n * NHEAD + h];
    // pass A: segment max (self-loop included)
    float m = lrelu(as1[n * NHEAD + h] + ad);
    for (int i = beg; i < end; ++i) {
        int s = col[i];
        m = fmaxf(m, lrelu(as1[s * NHEAD + h] + ad));
    }
    // pass B: weighted aggregate + denom
    float denom = 0.0f, acc = 0.0f;
    {
        float w = __expf(lrelu(as1[n * NHEAD + h] + ad) - m);
        denom += w;
        acc += w * Hp[(size_t)n * HD + lane];
    }
    for (int i = beg; i < end; ++i) {
        int s = col[i];
        float w = __expf(lrelu(as1[s * NHEAD + h] + ad) - m);
        denom += w;
        acc += w * Hp[(size_t)s * HD + lane];
    }
    float v = acc / (denom + 1e-16f) + b1[lane];
    H1out[(size_t)n * HD + lane] = v > 0.0f ? v : __expf(v) - 1.0f;
}

// ---------------- GEMM2 + alpha2 fused (wave per node) ----------------
__global__ __launch_bounds__(256) void gemm2_kernel(const float* __restrict__ H1,
                                                    const float* __restrict__ W2,
                                                    const float* __restrict__ asw,
                                                    const float* __restrict__ adw,
                                                    float* __restrict__ H2p,
                                                    float* __restrict__ as2,
                                                    float* __restrict__ ad2, int Nn) {
    __shared__ float W2s[HD * NC];
    __shared__ float asv[NC], adv[NC];
    for (int i = threadIdx.x; i < HD * NC; i += 256) W2s[i] = W2[i];
    if (threadIdx.x < NC) { asv[threadIdx.x] = asw[threadIdx.x]; adv[threadIdx.x] = adw[threadIdx.x]; }
    __syncthreads();
    int n = blockIdx.x * 4 + (threadIdx.x >> 6);
    int lane = threadIdx.x & 63;
    if (n >= Nn) return;
    float hval = H1[(size_t)n * HD + lane];
    float acc = 0.0f;
#pragma unroll
    for (int k = 0; k < HD; ++k) {
        float hk = __shfl(hval, k);
        if (lane < NC) acc += hk * W2s[k * NC + lane];
    }
    float sa = (lane < NC) ? acc * asv[lane] : 0.0f;
    float da = (lane < NC) ? acc * adv[lane] : 0.0f;
#pragma unroll
    for (int m = 1; m < 64; m <<= 1) { sa += __shfl_xor(sa, m); da += __shfl_xor(da, m); }
    if (lane == 0) { as2[n] = sa; ad2[n] = da; }
    if (lane < NC) H2p[(size_t)n * NC + lane] = acc;
}

// ---------------- agg2: edge softmax + aggregate + bias + log_softmax ----------------
__global__ __launch_bounds__(256) void agg2_kernel(const float* __restrict__ H2p,
                                                   const float* __restrict__ as2,
                                                   const float* __restrict__ ad2,
                                                   const int* __restrict__ rp,
                                                   const int* __restrict__ col,
                                                   const float* __restrict__ b2,
                                                   float* __restrict__ out, int Nn) {
    int n = blockIdx.x * 4 + (threadIdx.x >> 6);
    int lane = threadIdx.x & 63;
    if (n >= Nn) return;
    int beg = rp[n], end = rp[n + 1];
    float ad = ad2[n];
    float m = lrelu(as2[n] + ad);
    for (int i = beg; i < end; ++i) {
        m = fmaxf(m, lrelu(as2[col[i]] + ad));
    }
    float denom = 0.0f, acc = 0.0f;
    {
        float w = __expf(lrelu(as2[n] + ad) - m);
        denom += w;
        if (lane < NC) acc += w * H2p[(size_t)n * NC + lane];
    }
    for (int i = beg; i < end; ++i) {
        int s = col[i];
        float w = __expf(lrelu(as2[s] + ad) - m);
        denom += w;
        if (lane < NC) acc += w * H2p[(size_t)s * NC + lane];
    }
    float v = (lane < NC) ? acc / (denom + 1e-16f) + b2[lane] : -INFINITY;
    // log_softmax over 40 lanes
    float mx = v;
#pragma unroll
    for (int mm = 1; mm < 64; mm <<= 1) mx = fmaxf(mx, __shfl_xor(mx, mm));
    float ex = (lane < NC) ? __expf(v - mx) : 0.0f;
    float sum = ex;
#pragma unroll
    for (int mm = 1; mm < 64; mm <<= 1) sum += __shfl_xor(sum, mm);
    if (lane < NC) out[(size_t)n * NC + lane] = v - mx - __logf(sum);
}

extern "C" void kernel_launch(void* const* d_in, const int* in_sizes, int n_in,
                              void* d_out, int out_size, void* d_ws, size_t ws_size,
                              hipStream_t stream) {
    const float* x    = (const float*)d_in[0];
    const int*   ei   = (const int*)d_in[1];
    const float* W1   = (const float*)d_in[2];
    const float* as1w = (const float*)d_in[3];
    const float* ad1w = (const float*)d_in[4];
    const float* b1   = (const float*)d_in[5];
    const float* W2   = (const float*)d_in[6];
    const float* as2w = (const float*)d_in[7];
    const float* ad2w = (const float*)d_in[8];
    const float* b2   = (const float*)d_in[9];
    float* out = (float*)d_out;

    int Nn = in_sizes[0] / F_IN;
    int E  = in_sizes[1] / 2;
    const int* srcv = ei;
    const int* dstv = ei + E;

    // workspace layout
    char* ws = (char*)d_ws;
    size_t off = 0;
    auto alloc = [&](size_t bytes) { size_t cur = off; off += (bytes + 255) & ~255ULL; return cur; };
    float* h1p  = (float*)(ws + alloc((size_t)Nn * HD * 4));
    float* h1   = (float*)(ws + alloc((size_t)Nn * HD * 4));
    float* as1v = (float*)(ws + alloc((size_t)Nn * NHEAD * 4));
    float* ad1v = (float*)(ws + alloc((size_t)Nn * NHEAD * 4));
    float* h2p  = (float*)(ws + alloc((size_t)Nn * NC * 4));
    float* as2v = (float*)(ws + alloc((size_t)Nn * 4));
    float* ad2v = (float*)(ws + alloc((size_t)Nn * 4));
    int* deg  = (int*)(ws + alloc((size_t)Nn * 4));
    int* incl = (int*)(ws + alloc((size_t)Nn * 4));
    int* rp   = (int*)(ws + alloc((size_t)(Nn + 1) * 4));
    int* wr   = (int*)(ws + alloc((size_t)Nn * 4));
    int* col  = (int*)(ws + alloc((size_t)E * 4));
    int* bsum = (int*)(ws + alloc(256 * 4));

    int nb = (Nn + 1023) / 1024;

    hipMemsetAsync(deg, 0, (size_t)Nn * 4, stream);
    count_kernel<<<(E + 255) / 256, 256, 0, stream>>>(dstv, deg, E);
    scanA_kernel<<<nb, 256, 0, stream>>>(deg, incl, bsum, Nn);
    scanB_kernel<<<1, 64, 0, stream>>>(bsum, nb);
    scanC_kernel<<<(Nn + 255) / 256, 256, 0, stream>>>(incl, bsum, deg, rp, wr, Nn);
    scatter_kernel<<<(E + 255) / 256, 256, 0, stream>>>(srcv, dstv, wr, col, E);

    gemm1_kernel<<<(Nn + BM - 1) / BM, 256, 0, stream>>>(x, W1, h1p, Nn);
    alpha1_kernel<<<(Nn + 3) / 4, 256, 0, stream>>>(h1p, as1w, ad1w, as1v, ad1v, Nn);
    agg1_kernel<<<(Nn + 3) / 4, 256, 0, stream>>>(h1p, as1v, ad1v, rp, col, b1, h1, Nn);
    gemm2_kernel<<<(Nn + 3) / 4, 256, 0, stream>>>(h1, W2, as2w, ad2w, h2p, as2v, ad2v, Nn);
    agg2_kernel<<<(Nn + 3) / 4, 256, 0, stream>>>(h2p, as2v, ad2v, rp, col, b2, out, Nn);
}

// Round 3
// 678.795 us; speedup vs baseline: 1.3910x; 1.3910x over previous
//
#include <hip/hip_runtime.h>

#define F_IN   512
#define HD     64     // H*D layer-1 output width
#define NHEAD  8
#define DIMH   8
#define NC     40     // classes
#define NEG    0.2f

__device__ __forceinline__ float lrelu(float x) { return x > 0.0f ? x : NEG * x; }

// ---------------- CSR build ----------------
__global__ void count_kernel(const int* __restrict__ dst, int* __restrict__ deg, int E) {
    int e = blockIdx.x * 256 + threadIdx.x;
    if (e < E) atomicAdd(&deg[dst[e]], 1);
}

__global__ __launch_bounds__(256) void scanA_kernel(const int* __restrict__ deg,
                                                    int* __restrict__ incl,
                                                    int* __restrict__ bsum, int Nn) {
    __shared__ int wsum[4];
    int t = threadIdx.x, b = blockIdx.x;
    int base = b * 1024 + t * 4;
    int v0 = (base + 0) < Nn ? deg[base + 0] : 0;
    int v1 = (base + 1) < Nn ? deg[base + 1] : 0;
    int v2 = (base + 2) < Nn ? deg[base + 2] : 0;
    int v3 = (base + 3) < Nn ? deg[base + 3] : 0;
    int p0 = v0, p1 = p0 + v1, p2 = p1 + v2, p3 = p2 + v3;
    int lane = t & 63, w = t >> 6;
    int sc = p3;
    for (int off = 1; off < 64; off <<= 1) {
        int u = __shfl_up(sc, off);
        if (lane >= off) sc += u;
    }
    if (lane == 63) wsum[w] = sc;
    __syncthreads();
    int woff = 0;
#pragma unroll
    for (int i = 0; i < 4; ++i) if (i < w) woff += wsum[i];
    int excl = woff + sc - p3;
    if (base + 0 < Nn) incl[base + 0] = excl + p0;
    if (base + 1 < Nn) incl[base + 1] = excl + p1;
    if (base + 2 < Nn) incl[base + 2] = excl + p2;
    if (base + 3 < Nn) incl[base + 3] = excl + p3;
    if (t == 0) bsum[b] = wsum[0] + wsum[1] + wsum[2] + wsum[3];
}

__global__ void scanB_kernel(int* __restrict__ bsum, int nb) {
    int lane = threadIdx.x;  // 64 threads
    int a = lane < nb ? bsum[lane] : 0;
    int c = (lane + 64) < nb ? bsum[lane + 64] : 0;
    int sa = a, sc2 = c;
    for (int off = 1; off < 64; off <<= 1) {
        int u = __shfl_up(sa, off);  if (lane >= off) sa += u;
        int u2 = __shfl_up(sc2, off); if (lane >= off) sc2 += u2;
    }
    int totA = __shfl(sa, 63);
    int ea = sa - a;
    int ec = totA + sc2 - c;
    if (lane < nb) bsum[lane] = ea;
    if (lane + 64 < nb) bsum[lane + 64] = ec;
}

__global__ void scanC_kernel(const int* __restrict__ incl, const int* __restrict__ bsum,
                             const int* __restrict__ deg, int* __restrict__ rp,
                             int* __restrict__ wr, int Nn) {
    int i = blockIdx.x * 256 + threadIdx.x;
    if (i == 0) rp[0] = 0;
    if (i < Nn) {
        int v = incl[i] + bsum[i >> 10];
        rp[i + 1] = v;
        wr[i] = v - deg[i];
    }
}

__global__ void scatter_kernel(const int* __restrict__ src, const int* __restrict__ dst,
                               int* __restrict__ wr, int* __restrict__ col, int E) {
    int e = blockIdx.x * 256 + threadIdx.x;
    if (e < E) {
        int d = dst[e];
        int pos = atomicAdd(&wr[d], 1);
        col[pos] = src[e];
    }
}

// ---------------- GEMM1: h1p = x @ W1   (Nn x 512) * (512 x 64) ----------------
#define BM 64
#define BK 32
__global__ __launch_bounds__(256) void gemm1_kernel(const float* __restrict__ X,
                                                    const float* __restrict__ W,
                                                    float* __restrict__ Hout, int Nn) {
    __shared__ float As[BK][BM + 4];  // transposed: As[k][row]
    __shared__ float Bs[BK][HD + 4];
    int tid = threadIdx.x;
    int row0 = blockIdx.x * BM;
    float acc[4][4] = {{0}};
    int tr = tid / 16, tc = tid % 16;
    for (int k0 = 0; k0 < F_IN; k0 += BK) {
#pragma unroll
        for (int i = 0; i < 2; ++i) {
            int idx = tid + i * 256;   // 0..511
            int r = idx >> 3;
            int kk = (idx & 7) * 4;
            float4 v = make_float4(0, 0, 0, 0);
            int gr = row0 + r;
            if (gr < Nn) v = *reinterpret_cast<const float4*>(&X[(size_t)gr * F_IN + k0 + kk]);
            As[kk + 0][r] = v.x; As[kk + 1][r] = v.y; As[kk + 2][r] = v.z; As[kk + 3][r] = v.w;
        }
#pragma unroll
        for (int i = 0; i < 2; ++i) {
            int idx = tid + i * 256;
            int kk = idx >> 4;          // 0..31
            int c = (idx & 15) * 4;
            float4 v = *reinterpret_cast<const float4*>(&W[(size_t)(k0 + kk) * HD + c]);
            *reinterpret_cast<float4*>(&Bs[kk][c]) = v;
        }
        __syncthreads();
#pragma unroll
        for (int k = 0; k < BK; ++k) {
            float4 a = *reinterpret_cast<const float4*>(&As[k][tr * 4]);
            float4 b = *reinterpret_cast<const float4*>(&Bs[k][tc * 4]);
            acc[0][0] += a.x * b.x; acc[0][1] += a.x * b.y; acc[0][2] += a.x * b.z; acc[0][3] += a.x * b.w;
            acc[1][0] += a.y * b.x; acc[1][1] += a.y * b.y; acc[1][2] += a.y * b.z; acc[1][3] += a.y * b.w;
            acc[2][0] += a.z * b.x; acc[2][1] += a.z * b.y; acc[2][2] += a.z * b.z; acc[2][3] += a.z * b.w;
            acc[3][0] += a.w * b.x; acc[3][1] += a.w * b.y; acc[3][2] += a.w * b.z; acc[3][3] += a.w * b.w;
        }
        __syncthreads();
    }
#pragma unroll
    for (int i = 0; i < 4; ++i) {
        int gr = row0 + tr * 4 + i;
        if (gr < Nn) {
            float4 v = make_float4(acc[i][0], acc[i][1], acc[i][2], acc[i][3]);
            *reinterpret_cast<float4*>(&Hout[(size_t)gr * HD + tc * 4]) = v;
        }
    }
}

// ---------------- alpha1: per-node per-head attention logits ----------------
__global__ void alpha1_kernel(const float* __restrict__ Hp, const float* __restrict__ att_s,
                              const float* __restrict__ att_d, float* __restrict__ as_o,
                              float* __restrict__ ad_o, int Nn) {
    int n = blockIdx.x * 4 + (threadIdx.x >> 6);
    int lane = threadIdx.x & 63;
    if (n >= Nn) return;
    float h = Hp[(size_t)n * HD + lane];
    float s = h * att_s[lane];
    float d = h * att_d[lane];
#pragma unroll
    for (int m = 1; m < 8; m <<= 1) { s += __shfl_xor(s, m); d += __shfl_xor(d, m); }
    if ((lane & 7) == 0) {
        as_o[n * NHEAD + (lane >> 3)] = s;
        ad_o[n * NHEAD + (lane >> 3)] = d;
    }
}

// ---------------- softmax1: per-node per-head edge softmax (lane-parallel) ----------------
// lanes = 8 edge-slots x 8 heads. Writes normalized alpha into ev1 (CSR-ordered, E*8),
// self-loop weight into selfw1 (N*8).
__global__ __launch_bounds__(256) void softmax1_kernel(const int* __restrict__ col,
                                                       const int* __restrict__ rp,
                                                       const float* __restrict__ as1,
                                                       const float* __restrict__ ad1,
                                                       float* __restrict__ ev1,
                                                       float* __restrict__ selfw1, int Nn) {
    int n = blockIdx.x * 4 + (threadIdx.x >> 6);
    int lane = threadIdx.x & 63;
    if (n >= Nn) return;
    int e8 = lane >> 3, h = lane & 7;
    int beg = rp[n], end = rp[n + 1];
    float adv = ad1[n * NHEAD + h];
    float sl = lrelu(as1[n * NHEAD + h] + adv);
    float m = sl;
    for (int t = beg + e8; t < end; t += 8) {
        int s = col[t];
        float ev = lrelu(as1[s * NHEAD + h] + adv);
        ev1[(size_t)t * NHEAD + h] = ev;
        m = fmaxf(m, ev);
    }
    m = fmaxf(m, __shfl_xor(m, 8));
    m = fmaxf(m, __shfl_xor(m, 16));
    m = fmaxf(m, __shfl_xor(m, 32));
    float denom = (e8 == 0) ? __expf(sl - m) : 0.0f;
    for (int t = beg + e8; t < end; t += 8) {
        float ex = __expf(ev1[(size_t)t * NHEAD + h] - m);
        ev1[(size_t)t * NHEAD + h] = ex;
        denom += ex;
    }
    denom += __shfl_xor(denom, 8);
    denom += __shfl_xor(denom, 16);
    denom += __shfl_xor(denom, 32);
    float invd = 1.0f / (denom + 1e-16f);
    for (int t = beg + e8; t < end; t += 8) {
        ev1[(size_t)t * NHEAD + h] *= invd;
    }
    if (e8 == 0) selfw1[n * NHEAD + h] = __expf(sl - m) * invd;
}

// ---------------- agg1: weighted aggregate + bias + ELU (4 edge-slots x float4) ----------------
__global__ __launch_bounds__(256) void agg1_kernel(const float* __restrict__ Hp,
                                                   const float* __restrict__ alpha,
                                                   const int* __restrict__ col,
                                                   const int* __restrict__ rp,
                                                   const float* __restrict__ selfw1,
                                                   const float* __restrict__ b1,
                                                   float* __restrict__ H1out, int Nn) {
    int n = blockIdx.x * 4 + (threadIdx.x >> 6);
    int lane = threadIdx.x & 63;
    if (n >= Nn) return;
    int slot = lane >> 4, l16 = lane & 15;
    int beg = rp[n], end = rp[n + 1];
    float4 acc = make_float4(0, 0, 0, 0);
    for (int t = beg + slot; t < end; t += 4) {
        int s = col[t];
        float a = alpha[(size_t)t * NHEAD + (l16 >> 1)];
        float4 v = *reinterpret_cast<const float4*>(&Hp[(size_t)s * HD + l16 * 4]);
        acc.x += a * v.x; acc.y += a * v.y; acc.z += a * v.z; acc.w += a * v.w;
    }
#pragma unroll
    for (int mask = 16; mask < 64; mask <<= 1) {
        acc.x += __shfl_xor(acc.x, mask);
        acc.y += __shfl_xor(acc.y, mask);
        acc.z += __shfl_xor(acc.z, mask);
        acc.w += __shfl_xor(acc.w, mask);
    }
    if (slot == 0) {
        float a = selfw1[n * NHEAD + (l16 >> 1)];
        float4 v = *reinterpret_cast<const float4*>(&Hp[(size_t)n * HD + l16 * 4]);
        acc.x += a * v.x; acc.y += a * v.y; acc.z += a * v.z; acc.w += a * v.w;
        float4 bb = *reinterpret_cast<const float4*>(&b1[l16 * 4]);
        acc.x += bb.x; acc.y += bb.y; acc.z += bb.z; acc.w += bb.w;
        acc.x = acc.x > 0.0f ? acc.x : __expf(acc.x) - 1.0f;
        acc.y = acc.y > 0.0f ? acc.y : __expf(acc.y) - 1.0f;
        acc.z = acc.z > 0.0f ? acc.z : __expf(acc.z) - 1.0f;
        acc.w = acc.w > 0.0f ? acc.w : __expf(acc.w) - 1.0f;
        *reinterpret_cast<float4*>(&H1out[(size_t)n * HD + l16 * 4]) = acc;
    }
}

// ---------------- GEMM2 + alpha2 fused (wave per node) ----------------
__global__ __launch_bounds__(256) void gemm2_kernel(const float* __restrict__ H1,
                                                    const float* __restrict__ W2,
                                                    const float* __restrict__ asw,
                                                    const float* __restrict__ adw,
                                                    float* __restrict__ H2p,
                                                    float* __restrict__ as2,
                                                    float* __restrict__ ad2, int Nn) {
    __shared__ float W2s[HD * NC];
    __shared__ float asv[NC], adv[NC];
    for (int i = threadIdx.x; i < HD * NC; i += 256) W2s[i] = W2[i];
    if (threadIdx.x < NC) { asv[threadIdx.x] = asw[threadIdx.x]; adv[threadIdx.x] = adw[threadIdx.x]; }
    __syncthreads();
    int n = blockIdx.x * 4 + (threadIdx.x >> 6);
    int lane = threadIdx.x & 63;
    if (n >= Nn) return;
    float hval = H1[(size_t)n * HD + lane];
    float acc = 0.0f;
#pragma unroll
    for (int k = 0; k < HD; ++k) {
        float hk = __shfl(hval, k);
        if (lane < NC) acc += hk * W2s[k * NC + lane];
    }
    float sa = (lane < NC) ? acc * asv[lane] : 0.0f;
    float da = (lane < NC) ? acc * adv[lane] : 0.0f;
#pragma unroll
    for (int m = 1; m < 64; m <<= 1) { sa += __shfl_xor(sa, m); da += __shfl_xor(da, m); }
    if (lane == 0) { as2[n] = sa; ad2[n] = da; }
    if (lane < NC) H2p[(size_t)n * NC + lane] = acc;
}

// ---------------- softmax2: per-node edge softmax (64 edges/iter) ----------------
__global__ __launch_bounds__(256) void softmax2_kernel(const int* __restrict__ col,
                                                       const int* __restrict__ rp,
                                                       const float* __restrict__ as2,
                                                       const float* __restrict__ ad2,
                                                       float* __restrict__ ev2,
                                                       float* __restrict__ selfw2, int Nn) {
    int n = blockIdx.x * 4 + (threadIdx.x >> 6);
    int lane = threadIdx.x & 63;
    if (n >= Nn) return;
    int beg = rp[n], end = rp[n + 1];
    float adv = ad2[n];
    float sl = lrelu(as2[n] + adv);
    float m = sl;
    for (int t = beg + lane; t < end; t += 64) {
        int s = col[t];
        float ev = lrelu(as2[s] + adv);
        ev2[t] = ev;
        m = fmaxf(m, ev);
    }
#pragma unroll
    for (int mask = 1; mask < 64; mask <<= 1) m = fmaxf(m, __shfl_xor(m, mask));
    float denom = (lane == 0) ? __expf(sl - m) : 0.0f;
    for (int t = beg + lane; t < end; t += 64) {
        float ex = __expf(ev2[t] - m);
        ev2[t] = ex;
        denom += ex;
    }
#pragma unroll
    for (int mask = 1; mask < 64; mask <<= 1) denom += __shfl_xor(denom, mask);
    float invd = 1.0f / (denom + 1e-16f);
    for (int t = beg + lane; t < end; t += 64) ev2[t] *= invd;
    if (lane == 0) selfw2[n] = __expf(sl - m) * invd;
}

// ---------------- agg2: aggregate + bias + log_softmax (4 edge-slots x float4) ----------------
__global__ __launch_bounds__(256) void agg2_kernel(const float* __restrict__ H2p,
                                                   const float* __restrict__ alpha,
                                                   const int* __restrict__ col,
                                                   const int* __restrict__ rp,
                                                   const float* __restrict__ selfw2,
                                                   const float* __restrict__ b2,
                                                   float* __restrict__ out, int Nn) {
    int n = blockIdx.x * 4 + (threadIdx.x >> 6);
    int lane = threadIdx.x & 63;
    if (n >= Nn) return;
    int slot = lane >> 4, l16 = lane & 15;
    bool act = l16 < 10;
    int beg = rp[n], end = rp[n + 1];
    float4 acc = make_float4(0, 0, 0, 0);
    for (int t = beg + slot; t < end; t += 4) {
        int s = col[t];
        float a = alpha[t];
        if (act) {
            float4 v = *reinterpret_cast<const float4*>(&H2p[(size_t)s * NC + l16 * 4]);
            acc.x += a * v.x; acc.y += a * v.y; acc.z += a * v.z; acc.w += a * v.w;
        }
    }
#pragma unroll
    for (int mask = 16; mask < 64; mask <<= 1) {
        acc.x += __shfl_xor(acc.x, mask);
        acc.y += __shfl_xor(acc.y, mask);
        acc.z += __shfl_xor(acc.z, mask);
        acc.w += __shfl_xor(acc.w, mask);
    }
    // all 4 slots now hold identical sums; finish with all lanes active
    if (act) {
        float a = selfw2[n];
        float4 v = *reinterpret_cast<const float4*>(&H2p[(size_t)n * NC + l16 * 4]);
        float4 bb = *reinterpret_cast<const float4*>(&b2[l16 * 4]);
        acc.x += a * v.x + bb.x; acc.y += a * v.y + bb.y;
        acc.z += a * v.z + bb.z; acc.w += a * v.w + bb.w;
    }
    float mloc = act ? fmaxf(fmaxf(acc.x, acc.y), fmaxf(acc.z, acc.w)) : -INFINITY;
#pragma unroll
    for (int mask = 1; mask < 16; mask <<= 1) mloc = fmaxf(mloc, __shfl_xor(mloc, mask));
    float s4 = act ? (__expf(acc.x - mloc) + __expf(acc.y - mloc) +
                      __expf(acc.z - mloc) + __expf(acc.w - mloc)) : 0.0f;
#pragma unroll
    for (int mask = 1; mask < 16; mask <<= 1) s4 += __shfl_xor(s4, mask);
    float lse = mloc + __logf(s4);
    if (slot == 0 && act) {
        float4 o = make_float4(acc.x - lse, acc.y - lse, acc.z - lse, acc.w - lse);
        *reinterpret_cast<float4*>(&out[(size_t)n * NC + l16 * 4]) = o;
    }
}

extern "C" void kernel_launch(void* const* d_in, const int* in_sizes, int n_in,
                              void* d_out, int out_size, void* d_ws, size_t ws_size,
                              hipStream_t stream) {
    const float* x    = (const float*)d_in[0];
    const int*   ei   = (const int*)d_in[1];
    const float* W1   = (const float*)d_in[2];
    const float* as1w = (const float*)d_in[3];
    const float* ad1w = (const float*)d_in[4];
    const float* b1   = (const float*)d_in[5];
    const float* W2   = (const float*)d_in[6];
    const float* as2w = (const float*)d_in[7];
    const float* ad2w = (const float*)d_in[8];
    const float* b2   = (const float*)d_in[9];
    float* out = (float*)d_out;

    int Nn = in_sizes[0] / F_IN;
    int E  = in_sizes[1] / 2;
    const int* srcv = ei;
    const int* dstv = ei + E;

    // workspace layout
    char* ws = (char*)d_ws;
    size_t off = 0;
    auto alloc = [&](size_t bytes) { size_t cur = off; off += (bytes + 255) & ~255ULL; return cur; };
    float* h1p  = (float*)(ws + alloc((size_t)Nn * HD * 4));
    float* h1   = (float*)(ws + alloc((size_t)Nn * HD * 4));
    float* as1v = (float*)(ws + alloc((size_t)Nn * NHEAD * 4));
    float* ad1v = (float*)(ws + alloc((size_t)Nn * NHEAD * 4));
    float* h2p  = (float*)(ws + alloc((size_t)Nn * NC * 4));
    float* as2v = (float*)(ws + alloc((size_t)Nn * 4));
    float* ad2v = (float*)(ws + alloc((size_t)Nn * 4));
    int* deg  = (int*)(ws + alloc((size_t)Nn * 4));
    int* incl = (int*)(ws + alloc((size_t)Nn * 4));
    int* rp   = (int*)(ws + alloc((size_t)(Nn + 1) * 4));
    int* wr   = (int*)(ws + alloc((size_t)Nn * 4));
    int* col  = (int*)(ws + alloc((size_t)E * 4));
    int* bsum = (int*)(ws + alloc(256 * 4));
    float* ev1    = (float*)(ws + alloc((size_t)E * NHEAD * 4));
    float* selfw1 = (float*)(ws + alloc((size_t)Nn * NHEAD * 4));
    float* ev2    = (float*)(ws + alloc((size_t)E * 4));
    float* selfw2 = (float*)(ws + alloc((size_t)Nn * 4));

    int nb = (Nn + 1023) / 1024;

    hipMemsetAsync(deg, 0, (size_t)Nn * 4, stream);
    count_kernel<<<(E + 255) / 256, 256, 0, stream>>>(dstv, deg, E);
    scanA_kernel<<<nb, 256, 0, stream>>>(deg, incl, bsum, Nn);
    scanB_kernel<<<1, 64, 0, stream>>>(bsum, nb);
    scanC_kernel<<<(Nn + 255) / 256, 256, 0, stream>>>(incl, bsum, deg, rp, wr, Nn);
    scatter_kernel<<<(E + 255) / 256, 256, 0, stream>>>(srcv, dstv, wr, col, E);

    gemm1_kernel<<<(Nn + BM - 1) / BM, 256, 0, stream>>>(x, W1, h1p, Nn);
    alpha1_kernel<<<(Nn + 3) / 4, 256, 0, stream>>>(h1p, as1w, ad1w, as1v, ad1v, Nn);
    softmax1_kernel<<<(Nn + 3) / 4, 256, 0, stream>>>(col, rp, as1v, ad1v, ev1, selfw1, Nn);
    agg1_kernel<<<(Nn + 3) / 4, 256, 0, stream>>>(h1p, ev1, col, rp, selfw1, b1, h1, Nn);
    gemm2_kernel<<<(Nn + 3) / 4, 256, 0, stream>>>(h1, W2, as2w, ad2w, h2p, as2v, ad2v, Nn);
    softmax2_kernel<<<(Nn + 3) / 4, 256, 0, stream>>>(col, rp, as2v, ad2v, ev2, selfw2, Nn);
    agg2_kernel<<<(Nn + 3) / 4, 256, 0, stream>>>(h2p, ev2, col, rp, selfw2, b2, out, Nn);
}

// Round 4
// 512.185 us; speedup vs baseline: 1.8434x; 1.3253x over previous
//
#include <hip/hip_runtime.h>

#define F_IN   512
#define HD     64     // H*D layer-1 output width
#define NHEAD  8
#define DIMH   8
#define NC     40     // classes
#define NEG    0.2f

__device__ __forceinline__ float lrelu(float x) { return x > 0.0f ? x : NEG * x; }

// ---------------- CSR build ----------------
// count + rank in one pass: pos[e] = rank of edge e within its dst segment
__global__ void count_kernel(const int* __restrict__ dst, int* __restrict__ deg,
                             int* __restrict__ pos, int E) {
    int e = blockIdx.x * 256 + threadIdx.x;
    if (e < E) pos[e] = atomicAdd(&deg[dst[e]], 1);
}

__global__ __launch_bounds__(256) void scanA_kernel(const int* __restrict__ deg,
                                                    int* __restrict__ incl,
                                                    int* __restrict__ bsum, int Nn) {
    __shared__ int wsum[4];
    int t = threadIdx.x, b = blockIdx.x;
    int base = b * 1024 + t * 4;
    int v0 = (base + 0) < Nn ? deg[base + 0] : 0;
    int v1 = (base + 1) < Nn ? deg[base + 1] : 0;
    int v2 = (base + 2) < Nn ? deg[base + 2] : 0;
    int v3 = (base + 3) < Nn ? deg[base + 3] : 0;
    int p0 = v0, p1 = p0 + v1, p2 = p1 + v2, p3 = p2 + v3;
    int lane = t & 63, w = t >> 6;
    int sc = p3;
    for (int off = 1; off < 64; off <<= 1) {
        int u = __shfl_up(sc, off);
        if (lane >= off) sc += u;
    }
    if (lane == 63) wsum[w] = sc;
    __syncthreads();
    int woff = 0;
#pragma unroll
    for (int i = 0; i < 4; ++i) if (i < w) woff += wsum[i];
    int excl = woff + sc - p3;
    if (base + 0 < Nn) incl[base + 0] = excl + p0;
    if (base + 1 < Nn) incl[base + 1] = excl + p1;
    if (base + 2 < Nn) incl[base + 2] = excl + p2;
    if (base + 3 < Nn) incl[base + 3] = excl + p3;
    if (t == 0) bsum[b] = wsum[0] + wsum[1] + wsum[2] + wsum[3];
}

__global__ void scanB_kernel(int* __restrict__ bsum, int nb) {
    int lane = threadIdx.x;  // 64 threads
    int a = lane < nb ? bsum[lane] : 0;
    int c = (lane + 64) < nb ? bsum[lane + 64] : 0;
    int sa = a, sc2 = c;
    for (int off = 1; off < 64; off <<= 1) {
        int u = __shfl_up(sa, off);  if (lane >= off) sa += u;
        int u2 = __shfl_up(sc2, off); if (lane >= off) sc2 += u2;
    }
    int totA = __shfl(sa, 63);
    int ea = sa - a;
    int ec = totA + sc2 - c;
    if (lane < nb) bsum[lane] = ea;
    if (lane + 64 < nb) bsum[lane + 64] = ec;
}

__global__ void scanC_kernel(const int* __restrict__ incl, const int* __restrict__ bsum,
                             int* __restrict__ rp, int Nn) {
    int i = blockIdx.x * 256 + threadIdx.x;
    if (i == 0) rp[0] = 0;
    if (i < Nn) rp[i + 1] = incl[i] + bsum[i >> 10];
}

// atomic-free scatter: col[rp[d] + pos[e]] = src[e]
__global__ void scatter_kernel(const int* __restrict__ src, const int* __restrict__ dst,
                               const int* __restrict__ pos, const int* __restrict__ rp,
                               int* __restrict__ col, int E) {
    int e = blockIdx.x * 256 + threadIdx.x;
    if (e < E) {
        int d = dst[e];
        int p = rp[d] + pos[e];
        __builtin_nontemporal_store(src[e], &col[p]);
    }
}

// ---------------- GEMM1: h1p = x @ W1   (Nn x 512) * (512 x 64) ----------------
#define BM 64
#define BK 32
__global__ __launch_bounds__(256) void gemm1_kernel(const float* __restrict__ X,
                                                    const float* __restrict__ W,
                                                    float* __restrict__ Hout, int Nn) {
    __shared__ float As[BK][BM + 4];  // transposed: As[k][row]
    __shared__ float Bs[BK][HD + 4];
    int tid = threadIdx.x;
    int row0 = blockIdx.x * BM;
    float acc[4][4] = {{0}};
    int tr = tid / 16, tc = tid % 16;
    for (int k0 = 0; k0 < F_IN; k0 += BK) {
#pragma unroll
        for (int i = 0; i < 2; ++i) {
            int idx = tid + i * 256;   // 0..511
            int r = idx >> 3;
            int kk = (idx & 7) * 4;
            float4 v = make_float4(0, 0, 0, 0);
            int gr = row0 + r;
            if (gr < Nn) v = *reinterpret_cast<const float4*>(&X[(size_t)gr * F_IN + k0 + kk]);
            As[kk + 0][r] = v.x; As[kk + 1][r] = v.y; As[kk + 2][r] = v.z; As[kk + 3][r] = v.w;
        }
#pragma unroll
        for (int i = 0; i < 2; ++i) {
            int idx = tid + i * 256;
            int kk = idx >> 4;          // 0..31
            int c = (idx & 15) * 4;
            float4 v = *reinterpret_cast<const float4*>(&W[(size_t)(k0 + kk) * HD + c]);
            *reinterpret_cast<float4*>(&Bs[kk][c]) = v;
        }
        __syncthreads();
#pragma unroll
        for (int k = 0; k < BK; ++k) {
            float4 a = *reinterpret_cast<const float4*>(&As[k][tr * 4]);
            float4 b = *reinterpret_cast<const float4*>(&Bs[k][tc * 4]);
            acc[0][0] += a.x * b.x; acc[0][1] += a.x * b.y; acc[0][2] += a.x * b.z; acc[0][3] += a.x * b.w;
            acc[1][0] += a.y * b.x; acc[1][1] += a.y * b.y; acc[1][2] += a.y * b.z; acc[1][3] += a.y * b.w;
            acc[2][0] += a.z * b.x; acc[2][1] += a.z * b.y; acc[2][2] += a.z * b.z; acc[2][3] += a.z * b.w;
            acc[3][0] += a.w * b.x; acc[3][1] += a.w * b.y; acc[3][2] += a.w * b.z; acc[3][3] += a.w * b.w;
        }
        __syncthreads();
    }
#pragma unroll
    for (int i = 0; i < 4; ++i) {
        int gr = row0 + tr * 4 + i;
        if (gr < Nn) {
            float4 v = make_float4(acc[i][0], acc[i][1], acc[i][2], acc[i][3]);
            *reinterpret_cast<float4*>(&Hout[(size_t)gr * HD + tc * 4]) = v;
        }
    }
}

// ---------------- alpha1: per-node per-head attention logits ----------------
__global__ void alpha1_kernel(const float* __restrict__ Hp, const float* __restrict__ att_s,
                              const float* __restrict__ att_d, float* __restrict__ as_o,
                              float* __restrict__ ad_o, int Nn) {
    int n = blockIdx.x * 4 + (threadIdx.x >> 6);
    int lane = threadIdx.x & 63;
    if (n >= Nn) return;
    float h = Hp[(size_t)n * HD + lane];
    float s = h * att_s[lane];
    float d = h * att_d[lane];
#pragma unroll
    for (int m = 1; m < 8; m <<= 1) { s += __shfl_xor(s, m); d += __shfl_xor(d, m); }
    if ((lane & 7) == 0) {
        as_o[n * NHEAD + (lane >> 3)] = s;
        ad_o[n * NHEAD + (lane >> 3)] = d;
    }
}

// ---------------- softmax1: max + exp + denom (normalization deferred) ----------------
// lanes = 8 edge-slots x 8 heads. ev1[t*8+h] = exp(e - m) unnormalized;
// selfw1[n*8+h] = exp(self - m); invd1[n*8+h] = 1/denom.
__global__ __launch_bounds__(256) void softmax1_kernel(const int* __restrict__ col,
                                                       const int* __restrict__ rp,
                                                       const float* __restrict__ as1,
                                                       const float* __restrict__ ad1,
                                                       float* __restrict__ ev1,
                                                       float* __restrict__ selfw1,
                                                       float* __restrict__ invd1, int Nn) {
    int n = blockIdx.x * 4 + (threadIdx.x >> 6);
    int lane = threadIdx.x & 63;
    if (n >= Nn) return;
    int e8 = lane >> 3, h = lane & 7;
    int beg = rp[n], end = rp[n + 1];
    float adv = ad1[n * NHEAD + h];
    float sl = lrelu(as1[n * NHEAD + h] + adv);
    float m = sl;
    for (int t = beg + e8; t < end; t += 8) {
        int s = col[t];
        m = fmaxf(m, lrelu(as1[s * NHEAD + h] + adv));
    }
    m = fmaxf(m, __shfl_xor(m, 8));
    m = fmaxf(m, __shfl_xor(m, 16));
    m = fmaxf(m, __shfl_xor(m, 32));
    float denom = (e8 == 0) ? __expf(sl - m) : 0.0f;
    for (int t = beg + e8; t < end; t += 8) {
        int s = col[t];
        float ex = __expf(lrelu(as1[s * NHEAD + h] + adv) - m);
        ev1[(size_t)t * NHEAD + h] = ex;
        denom += ex;
    }
    denom += __shfl_xor(denom, 8);
    denom += __shfl_xor(denom, 16);
    denom += __shfl_xor(denom, 32);
    if (e8 == 0) {
        selfw1[n * NHEAD + h] = __expf(sl - m);
        invd1[n * NHEAD + h] = 1.0f / (denom + 1e-16f);
    }
}

// ---------------- agg1: weighted aggregate (deferred norm) + bias + ELU ----------------
__global__ __launch_bounds__(256) void agg1_kernel(const float* __restrict__ Hp,
                                                   const float* __restrict__ alpha,
                                                   const int* __restrict__ col,
                                                   const int* __restrict__ rp,
                                                   const float* __restrict__ selfw1,
                                                   const float* __restrict__ invd1,
                                                   const float* __restrict__ b1,
                                                   float* __restrict__ H1out, int Nn) {
    int n = blockIdx.x * 4 + (threadIdx.x >> 6);
    int lane = threadIdx.x & 63;
    if (n >= Nn) return;
    int slot = lane >> 4, l16 = lane & 15;
    int beg = rp[n], end = rp[n + 1];
    float4 acc = make_float4(0, 0, 0, 0);
    for (int t = beg + slot; t < end; t += 4) {
        int s = col[t];
        float a = alpha[(size_t)t * NHEAD + (l16 >> 1)];
        float4 v = *reinterpret_cast<const float4*>(&Hp[(size_t)s * HD + l16 * 4]);
        acc.x += a * v.x; acc.y += a * v.y; acc.z += a * v.z; acc.w += a * v.w;
    }
#pragma unroll
    for (int mask = 16; mask < 64; mask <<= 1) {
        acc.x += __shfl_xor(acc.x, mask);
        acc.y += __shfl_xor(acc.y, mask);
        acc.z += __shfl_xor(acc.z, mask);
        acc.w += __shfl_xor(acc.w, mask);
    }
    if (slot == 0) {
        float a = selfw1[n * NHEAD + (l16 >> 1)];
        float invd = invd1[n * NHEAD + (l16 >> 1)];
        float4 v = *reinterpret_cast<const float4*>(&Hp[(size_t)n * HD + l16 * 4]);
        acc.x += a * v.x; acc.y += a * v.y; acc.z += a * v.z; acc.w += a * v.w;
        float4 bb = *reinterpret_cast<const float4*>(&b1[l16 * 4]);
        acc.x = acc.x * invd + bb.x; acc.y = acc.y * invd + bb.y;
        acc.z = acc.z * invd + bb.z; acc.w = acc.w * invd + bb.w;
        acc.x = acc.x > 0.0f ? acc.x : __expf(acc.x) - 1.0f;
        acc.y = acc.y > 0.0f ? acc.y : __expf(acc.y) - 1.0f;
        acc.z = acc.z > 0.0f ? acc.z : __expf(acc.z) - 1.0f;
        acc.w = acc.w > 0.0f ? acc.w : __expf(acc.w) - 1.0f;
        *reinterpret_cast<float4*>(&H1out[(size_t)n * HD + l16 * 4]) = acc;
    }
}

// ---------------- GEMM2: tiled (64 rows/block) + fused alpha2 ----------------
#define G2R 64
__global__ __launch_bounds__(256) void gemm2_kernel(const float* __restrict__ H1,
                                                    const float* __restrict__ W2,
                                                    const float* __restrict__ asw,
                                                    const float* __restrict__ adw,
                                                    float* __restrict__ H2p,
                                                    float* __restrict__ as2,
                                                    float* __restrict__ ad2, int Nn) {
    __shared__ float Hs[G2R][HD + 1];
    __shared__ float W2s[HD][NC];
    __shared__ float asv[NC], adv[NC];
    int tid = threadIdx.x;
    for (int i = tid; i < HD * NC; i += 256) W2s[i / NC][i % NC] = W2[i];
    if (tid < NC) { asv[tid] = asw[tid]; adv[tid] = adw[tid]; }
    int row0 = blockIdx.x * G2R;
#pragma unroll
    for (int i = 0; i < 4; ++i) {
        int linear = i * 1024 + tid * 4;
        int r = linear >> 6, c = linear & 63;
        int gr = row0 + r;
        float4 v = make_float4(0, 0, 0, 0);
        if (gr < Nn) v = *reinterpret_cast<const float4*>(&H1[(size_t)gr * HD + c]);
        Hs[r][c + 0] = v.x; Hs[r][c + 1] = v.y; Hs[r][c + 2] = v.z; Hs[r][c + 3] = v.w;
    }
    __syncthreads();
    int row = tid >> 2, cg = tid & 3;      // 64 rows x 4 col-groups of 10
    int gr = row0 + row;
    float acc[10];
#pragma unroll
    for (int j = 0; j < 10; ++j) acc[j] = 0.0f;
    for (int k = 0; k < HD; ++k) {
        float a = Hs[row][k];
#pragma unroll
        for (int j = 0; j < 10; ++j) acc[j] += a * W2s[k][cg * 10 + j];
    }
    float sa = 0.0f, da = 0.0f;
#pragma unroll
    for (int j = 0; j < 10; ++j) {
        sa += acc[j] * asv[cg * 10 + j];
        da += acc[j] * adv[cg * 10 + j];
    }
    sa += __shfl_xor(sa, 1); sa += __shfl_xor(sa, 2);
    da += __shfl_xor(da, 1); da += __shfl_xor(da, 2);
    if (gr < Nn) {
        if (cg == 0) { as2[gr] = sa; ad2[gr] = da; }
        float* o = &H2p[(size_t)gr * NC + cg * 10];
#pragma unroll
        for (int j = 0; j < 10; j += 2) {
            *reinterpret_cast<float2*>(&o[j]) = make_float2(acc[j], acc[j + 1]);
        }
    }
}

// ---------------- softmax2: max + exp + denom (normalization deferred) ----------------
__global__ __launch_bounds__(256) void softmax2_kernel(const int* __restrict__ col,
                                                       const int* __restrict__ rp,
                                                       const float* __restrict__ as2,
                                                       const float* __restrict__ ad2,
                                                       float* __restrict__ ev2,
                                                       float* __restrict__ selfw2,
                                                       float* __restrict__ invd2, int Nn) {
    int n = blockIdx.x * 4 + (threadIdx.x >> 6);
    int lane = threadIdx.x & 63;
    if (n >= Nn) return;
    int beg = rp[n], end = rp[n + 1];
    float adv = ad2[n];
    float sl = lrelu(as2[n] + adv);
    float m = sl;
    for (int t = beg + lane; t < end; t += 64) {
        m = fmaxf(m, lrelu(as2[col[t]] + adv));
    }
#pragma unroll
    for (int mask = 1; mask < 64; mask <<= 1) m = fmaxf(m, __shfl_xor(m, mask));
    float denom = (lane == 0) ? __expf(sl - m) : 0.0f;
    for (int t = beg + lane; t < end; t += 64) {
        float ex = __expf(lrelu(as2[col[t]] + adv) - m);
        ev2[t] = ex;
        denom += ex;
    }
#pragma unroll
    for (int mask = 1; mask < 64; mask <<= 1) denom += __shfl_xor(denom, mask);
    if (lane == 0) {
        selfw2[n] = __expf(sl - m);
        invd2[n] = 1.0f / (denom + 1e-16f);
    }
}

// ---------------- agg2: aggregate (deferred norm) + bias + log_softmax ----------------
__global__ __launch_bounds__(256) void agg2_kernel(const float* __restrict__ H2p,
                                                   const float* __restrict__ alpha,
                                                   const int* __restrict__ col,
                                                   const int* __restrict__ rp,
                                                   const float* __restrict__ selfw2,
                                                   const float* __restrict__ invd2,
                                                   const float* __restrict__ b2,
                                                   float* __restrict__ out, int Nn) {
    int n = blockIdx.x * 4 + (threadIdx.x >> 6);
    int lane = threadIdx.x & 63;
    if (n >= Nn) return;
    int slot = lane >> 4, l16 = lane & 15;
    bool act = l16 < 10;
    int beg = rp[n], end = rp[n + 1];
    float4 acc = make_float4(0, 0, 0, 0);
    for (int t = beg + slot; t < end; t += 4) {
        int s = col[t];
        float a = alpha[t];
        if (act) {
            float4 v = *reinterpret_cast<const float4*>(&H2p[(size_t)s * NC + l16 * 4]);
            acc.x += a * v.x; acc.y += a * v.y; acc.z += a * v.z; acc.w += a * v.w;
        }
    }
#pragma unroll
    for (int mask = 16; mask < 64; mask <<= 1) {
        acc.x += __shfl_xor(acc.x, mask);
        acc.y += __shfl_xor(acc.y, mask);
        acc.z += __shfl_xor(acc.z, mask);
        acc.w += __shfl_xor(acc.w, mask);
    }
    if (act) {
        float a = selfw2[n];
        float invd = invd2[n];
        float4 v = *reinterpret_cast<const float4*>(&H2p[(size_t)n * NC + l16 * 4]);
        float4 bb = *reinterpret_cast<const float4*>(&b2[l16 * 4]);
        acc.x = (acc.x + a * v.x) * invd + bb.x;
        acc.y = (acc.y + a * v.y) * invd + bb.y;
        acc.z = (acc.z + a * v.z) * invd + bb.z;
        acc.w = (acc.w + a * v.w) * invd + bb.w;
    }
    float mloc = act ? fmaxf(fmaxf(acc.x, acc.y), fmaxf(acc.z, acc.w)) : -INFINITY;
#pragma unroll
    for (int mask = 1; mask < 16; mask <<= 1) mloc = fmaxf(mloc, __shfl_xor(mloc, mask));
    float s4 = act ? (__expf(acc.x - mloc) + __expf(acc.y - mloc) +
                      __expf(acc.z - mloc) + __expf(acc.w - mloc)) : 0.0f;
#pragma unroll
    for (int mask = 1; mask < 16; mask <<= 1) s4 += __shfl_xor(s4, mask);
    float lse = mloc + __logf(s4);
    if (slot == 0 && act) {
        float4 o = make_float4(acc.x - lse, acc.y - lse, acc.z - lse, acc.w - lse);
        *reinterpret_cast<float4*>(&out[(size_t)n * NC + l16 * 4]) = o;
    }
}

extern "C" void kernel_launch(void* const* d_in, const int* in_sizes, int n_in,
                              void* d_out, int out_size, void* d_ws, size_t ws_size,
                              hipStream_t stream) {
    const float* x    = (const float*)d_in[0];
    const int*   ei   = (const int*)d_in[1];
    const float* W1   = (const float*)d_in[2];
    const float* as1w = (const float*)d_in[3];
    const float* ad1w = (const float*)d_in[4];
    const float* b1   = (const float*)d_in[5];
    const float* W2   = (const float*)d_in[6];
    const float* as2w = (const float*)d_in[7];
    const float* ad2w = (const float*)d_in[8];
    const float* b2   = (const float*)d_in[9];
    float* out = (float*)d_out;

    int Nn = in_sizes[0] / F_IN;
    int E  = in_sizes[1] / 2;
    const int* srcv = ei;
    const int* dstv = ei + E;

    // workspace layout
    char* ws = (char*)d_ws;
    size_t off = 0;
    auto alloc = [&](size_t bytes) { size_t cur = off; off += (bytes + 255) & ~255ULL; return cur; };
    float* h1p  = (float*)(ws + alloc((size_t)Nn * HD * 4));
    float* h1   = (float*)(ws + alloc((size_t)Nn * HD * 4));
    float* as1v = (float*)(ws + alloc((size_t)Nn * NHEAD * 4));
    float* ad1v = (float*)(ws + alloc((size_t)Nn * NHEAD * 4));
    float* h2p  = (float*)(ws + alloc((size_t)Nn * NC * 4));
    float* as2v = (float*)(ws + alloc((size_t)Nn * 4));
    float* ad2v = (float*)(ws + alloc((size_t)Nn * 4));
    int* deg  = (int*)(ws + alloc((size_t)Nn * 4));
    int* incl = (int*)(ws + alloc((size_t)Nn * 4));
    int* rp   = (int*)(ws + alloc((size_t)(Nn + 1) * 4));
    int* pos  = (int*)(ws + alloc((size_t)E * 4));
    int* col  = (int*)(ws + alloc((size_t)E * 4));
    int* bsum = (int*)(ws + alloc(256 * 4));
    float* ev1    = (float*)(ws + alloc((size_t)E * NHEAD * 4));
    float* selfw1 = (float*)(ws + alloc((size_t)Nn * NHEAD * 4));
    float* invd1  = (float*)(ws + alloc((size_t)Nn * NHEAD * 4));
    float* ev2    = (float*)(ws + alloc((size_t)E * 4));
    float* selfw2 = (float*)(ws + alloc((size_t)Nn * 4));
    float* invd2  = (float*)(ws + alloc((size_t)Nn * 4));

    int nb = (Nn + 1023) / 1024;

    hipMemsetAsync(deg, 0, (size_t)Nn * 4, stream);
    count_kernel<<<(E + 255) / 256, 256, 0, stream>>>(dstv, deg, pos, E);
    scanA_kernel<<<nb, 256, 0, stream>>>(deg, incl, bsum, Nn);
    scanB_kernel<<<1, 64, 0, stream>>>(bsum, nb);
    scanC_kernel<<<(Nn + 255) / 256, 256, 0, stream>>>(incl, bsum, rp, Nn);
    scatter_kernel<<<(E + 255) / 256, 256, 0, stream>>>(srcv, dstv, pos, rp, col, E);

    gemm1_kernel<<<(Nn + BM - 1) / BM, 256, 0, stream>>>(x, W1, h1p, Nn);
    alpha1_kernel<<<(Nn + 3) / 4, 256, 0, stream>>>(h1p, as1w, ad1w, as1v, ad1v, Nn);
    softmax1_kernel<<<(Nn + 3) / 4, 256, 0, stream>>>(col, rp, as1v, ad1v, ev1, selfw1, invd1, Nn);
    agg1_kernel<<<(Nn + 3) / 4, 256, 0, stream>>>(h1p, ev1, col, rp, selfw1, invd1, b1, h1, Nn);
    gemm2_kernel<<<(Nn + G2R - 1) / G2R, 256, 0, stream>>>(h1, W2, as2w, ad2w, h2p, as2v, ad2v, Nn);
    softmax2_kernel<<<(Nn + 3) / 4, 256, 0, stream>>>(col, rp, as2v, ad2v, ev2, selfw2, invd2, Nn);
    agg2_kernel<<<(Nn + 3) / 4, 256, 0, stream>>>(h2p, ev2, col, rp, selfw2, invd2, b2, out, Nn);
}

// Round 5
// 416.507 us; speedup vs baseline: 2.2669x; 1.2297x over previous
//
#include <hip/hip_runtime.h>

#define F_IN   512
#define HD     64     // H*D layer-1 output width
#define NHEAD  8
#define NC     40     // classes
#define NEG    0.2f

typedef __attribute__((ext_vector_type(8))) short bf16x8;
typedef __attribute__((ext_vector_type(4))) float f32x4;

__device__ __forceinline__ float lrelu(float x) { return x > 0.0f ? x : NEG * x; }

__device__ __forceinline__ short f2bf(float f) {
    unsigned u = __float_as_uint(f);
    u += 0x7FFF + ((u >> 16) & 1);   // RNE to bf16
    return (short)(u >> 16);
}
__device__ __forceinline__ float bf2f(short h) {
    return __uint_as_float(((unsigned)(unsigned short)h) << 16);
}

// ---------------- CSR build ----------------
__global__ void count_kernel(const int* __restrict__ dst, int* __restrict__ deg,
                             int* __restrict__ pos, int E) {
    int e = blockIdx.x * 256 + threadIdx.x;
    if (e < E) pos[e] = atomicAdd(&deg[dst[e]], 1);
}

__global__ __launch_bounds__(256) void scanA_kernel(const int* __restrict__ deg,
                                                    int* __restrict__ incl,
                                                    int* __restrict__ bsum, int Nn) {
    __shared__ int wsum[4];
    int t = threadIdx.x, b = blockIdx.x;
    int base = b * 1024 + t * 4;
    int v0 = (base + 0) < Nn ? deg[base + 0] : 0;
    int v1 = (base + 1) < Nn ? deg[base + 1] : 0;
    int v2 = (base + 2) < Nn ? deg[base + 2] : 0;
    int v3 = (base + 3) < Nn ? deg[base + 3] : 0;
    int p0 = v0, p1 = p0 + v1, p2 = p1 + v2, p3 = p2 + v3;
    int lane = t & 63, w = t >> 6;
    int sc = p3;
    for (int off = 1; off < 64; off <<= 1) {
        int u = __shfl_up(sc, off);
        if (lane >= off) sc += u;
    }
    if (lane == 63) wsum[w] = sc;
    __syncthreads();
    int woff = 0;
#pragma unroll
    for (int i = 0; i < 4; ++i) if (i < w) woff += wsum[i];
    int excl = woff + sc - p3;
    if (base + 0 < Nn) incl[base + 0] = excl + p0;
    if (base + 1 < Nn) incl[base + 1] = excl + p1;
    if (base + 2 < Nn) incl[base + 2] = excl + p2;
    if (base + 3 < Nn) incl[base + 3] = excl + p3;
    if (t == 0) bsum[b] = wsum[0] + wsum[1] + wsum[2] + wsum[3];
}

__global__ void scanB_kernel(int* __restrict__ bsum, int nb) {
    int lane = threadIdx.x;  // 64 threads
    int a = lane < nb ? bsum[lane] : 0;
    int c = (lane + 64) < nb ? bsum[lane + 64] : 0;
    int sa = a, sc2 = c;
    for (int off = 1; off < 64; off <<= 1) {
        int u = __shfl_up(sa, off);  if (lane >= off) sa += u;
        int u2 = __shfl_up(sc2, off); if (lane >= off) sc2 += u2;
    }
    int totA = __shfl(sa, 63);
    int ea = sa - a;
    int ec = totA + sc2 - c;
    if (lane < nb) bsum[lane] = ea;
    if (lane + 64 < nb) bsum[lane + 64] = ec;
}

__global__ void scanC_kernel(const int* __restrict__ incl, const int* __restrict__ bsum,
                             int* __restrict__ rp, int Nn) {
    int i = blockIdx.x * 256 + threadIdx.x;
    if (i == 0) rp[0] = 0;
    if (i < Nn) rp[i + 1] = incl[i] + bsum[i >> 10];
}

__global__ void scatter_kernel(const int* __restrict__ src, const int* __restrict__ dst,
                               const int* __restrict__ pos, const int* __restrict__ rp,
                               int* __restrict__ col, int E) {
    int e = blockIdx.x * 256 + threadIdx.x;
    if (e < E) {
        int d = dst[e];
        int p = rp[d] + pos[e];
        __builtin_nontemporal_store(src[e], &col[p]);
    }
}

// ---------------- GEMM1 (MFMA bf16x3): h1p = x @ W1, fused alpha1 epilogue ----------
// 128 rows/block, 4 waves; wave w owns rows w*32..w*32+31, all 64 cols.
// bf16x3: x = xh+xl, W = wh+wl; acc += xh*wh + xl*wh + xh*wl (error ~2^-18).
#define G1_BM 128
#define G1_BK 32
__global__ __launch_bounds__(256) void gemm1_kernel(const float* __restrict__ X,
                                                    const float* __restrict__ W,
                                                    const float* __restrict__ att_s,
                                                    const float* __restrict__ att_d,
                                                    float* __restrict__ Hout,
                                                    float* __restrict__ as1,
                                                    float* __restrict__ ad1, int Nn) {
    __shared__ short Ah[G1_BM][40], Al[G1_BM][40];   // pad 32->40 (80B stride: 2-way max)
    __shared__ short Bh[HD][40],   Bl[HD][40];       // W transposed: [col][k]
    int tid = threadIdx.x;
    int wid = tid >> 6, lane = tid & 63;
    int lrow = lane & 15, kgrp = lane >> 4;
    int row0 = blockIdx.x * G1_BM;

    float ats[4], atd[4];
#pragma unroll
    for (int fc = 0; fc < 4; ++fc) { ats[fc] = att_s[fc * 16 + lrow]; atd[fc] = att_d[fc * 16 + lrow]; }

    f32x4 acc[2][4];
#pragma unroll
    for (int fr = 0; fr < 2; ++fr)
#pragma unroll
        for (int fc = 0; fc < 4; ++fc) acc[fr][fc] = (f32x4){0.f, 0.f, 0.f, 0.f};

    for (int k0 = 0; k0 < F_IN; k0 += G1_BK) {
        // stage A: thread t -> row t>>1, 16 cols
        {
            int r = tid >> 1;
            int cb = (tid & 1) * 16;
            int gr = row0 + r;
            const float* src = X + (size_t)gr * F_IN + k0 + cb;
            bool valid = gr < Nn;
            short* ah = &Ah[r][cb];
            short* al = &Al[r][cb];
#pragma unroll
            for (int i = 0; i < 4; ++i) {
                float4 v = valid ? *reinterpret_cast<const float4*>(src + i * 4)
                                 : make_float4(0.f, 0.f, 0.f, 0.f);
                float fs[4] = {v.x, v.y, v.z, v.w};
#pragma unroll
                for (int j = 0; j < 4; ++j) {
                    short hh = f2bf(fs[j]);
                    ah[i * 4 + j] = hh;
                    al[i * 4 + j] = f2bf(fs[j] - bf2f(hh));
                }
            }
        }
        // stage B (transpose W tile): 32k x 64c
#pragma unroll
        for (int i = 0; i < 8; ++i) {
            int idx = tid + i * 256;
            int kk = idx >> 6, c = idx & 63;
            float wv = W[(size_t)(k0 + kk) * HD + c];
            short hh = f2bf(wv);
            Bh[c][kk] = hh;
            Bl[c][kk] = f2bf(wv - bf2f(hh));
        }
        __syncthreads();

        bf16x8 bh[4], bl[4];
#pragma unroll
        for (int fc = 0; fc < 4; ++fc) {
            bh[fc] = *reinterpret_cast<const bf16x8*>(&Bh[fc * 16 + lrow][kgrp * 8]);
            bl[fc] = *reinterpret_cast<const bf16x8*>(&Bl[fc * 16 + lrow][kgrp * 8]);
        }
#pragma unroll
        for (int fr = 0; fr < 2; ++fr) {
            bf16x8 ahf = *reinterpret_cast<const bf16x8*>(&Ah[wid * 32 + fr * 16 + lrow][kgrp * 8]);
            bf16x8 alf = *reinterpret_cast<const bf16x8*>(&Al[wid * 32 + fr * 16 + lrow][kgrp * 8]);
#pragma unroll
            for (int fc = 0; fc < 4; ++fc) {
                acc[fr][fc] = __builtin_amdgcn_mfma_f32_16x16x32_bf16(ahf, bh[fc], acc[fr][fc], 0, 0, 0);
                acc[fr][fc] = __builtin_amdgcn_mfma_f32_16x16x32_bf16(alf, bh[fc], acc[fr][fc], 0, 0, 0);
                acc[fr][fc] = __builtin_amdgcn_mfma_f32_16x16x32_bf16(ahf, bl[fc], acc[fr][fc], 0, 0, 0);
            }
        }
        __syncthreads();
    }

    // epilogue: store h + fused per-head attention logits
#pragma unroll
    for (int fr = 0; fr < 2; ++fr) {
#pragma unroll
        for (int r = 0; r < 4; ++r) {
            int gr = row0 + wid * 32 + fr * 16 + kgrp * 4 + r;
            float hv[4], sp[4], dp[4];
#pragma unroll
            for (int fc = 0; fc < 4; ++fc) {
                hv[fc] = acc[fr][fc][r];
                sp[fc] = hv[fc] * ats[fc];
                dp[fc] = hv[fc] * atd[fc];
            }
#pragma unroll
            for (int mask = 1; mask <= 4; mask <<= 1) {
#pragma unroll
                for (int fc = 0; fc < 4; ++fc) {
                    sp[fc] += __shfl_xor(sp[fc], mask);
                    dp[fc] += __shfl_xor(dp[fc], mask);
                }
            }
            if (gr < Nn) {
#pragma unroll
                for (int fc = 0; fc < 4; ++fc)
                    Hout[(size_t)gr * HD + fc * 16 + lrow] = hv[fc];
                if ((lane & 7) == 0) {
                    int hh = lrow >> 3;
#pragma unroll
                    for (int fc = 0; fc < 4; ++fc) {
                        as1[gr * NHEAD + fc * 2 + hh] = sp[fc];
                        ad1[gr * NHEAD + fc * 2 + hh] = dp[fc];
                    }
                }
            }
        }
    }
}

// ---------------- agg1: fused exp+denom+aggregate (no max pass) + bias + ELU -------
// logits bounded (|as+ad| <~ 8) so exp without max-shift is safe in fp32.
__global__ __launch_bounds__(256) void agg1_kernel(const float* __restrict__ Hp,
                                                   const float* __restrict__ as1,
                                                   const float* __restrict__ ad1,
                                                   const int* __restrict__ col,
                                                   const int* __restrict__ rp,
                                                   const float* __restrict__ b1,
                                                   float* __restrict__ H1out, int Nn) {
    int n = blockIdx.x * 4 + (threadIdx.x >> 6);
    int lane = threadIdx.x & 63;
    if (n >= Nn) return;
    int slot = lane >> 4, l16 = lane & 15, h = l16 >> 1;
    int beg = rp[n], end = rp[n + 1];
    float adv = ad1[n * NHEAD + h];
    float4 acc = make_float4(0.f, 0.f, 0.f, 0.f);
    float dw = 0.f;
    for (int t = beg + slot; t < end; t += 4) {
        int s = col[t];
        float w = __expf(lrelu(as1[s * NHEAD + h] + adv));
        dw += w;
        float4 v = *reinterpret_cast<const float4*>(&Hp[(size_t)s * HD + l16 * 4]);
        acc.x += w * v.x; acc.y += w * v.y; acc.z += w * v.z; acc.w += w * v.w;
    }
#pragma unroll
    for (int mask = 16; mask < 64; mask <<= 1) {
        acc.x += __shfl_xor(acc.x, mask);
        acc.y += __shfl_xor(acc.y, mask);
        acc.z += __shfl_xor(acc.z, mask);
        acc.w += __shfl_xor(acc.w, mask);
        dw    += __shfl_xor(dw, mask);
    }
    if (slot == 0) {
        float w = __expf(lrelu(as1[n * NHEAD + h] + adv));
        float4 v = *reinterpret_cast<const float4*>(&Hp[(size_t)n * HD + l16 * 4]);
        acc.x += w * v.x; acc.y += w * v.y; acc.z += w * v.z; acc.w += w * v.w;
        dw += w;
        float invd = 1.0f / (dw + 1e-16f);
        float4 bb = *reinterpret_cast<const float4*>(&b1[l16 * 4]);
        acc.x = acc.x * invd + bb.x; acc.y = acc.y * invd + bb.y;
        acc.z = acc.z * invd + bb.z; acc.w = acc.w * invd + bb.w;
        acc.x = acc.x > 0.0f ? acc.x : __expf(acc.x) - 1.0f;
        acc.y = acc.y > 0.0f ? acc.y : __expf(acc.y) - 1.0f;
        acc.z = acc.z > 0.0f ? acc.z : __expf(acc.z) - 1.0f;
        acc.w = acc.w > 0.0f ? acc.w : __expf(acc.w) - 1.0f;
        *reinterpret_cast<float4*>(&H1out[(size_t)n * HD + l16 * 4]) = acc;
    }
}

// ---------------- GEMM2: tiled (64 rows/block) + fused alpha2 ----------------
#define G2R 64
__global__ __launch_bounds__(256) void gemm2_kernel(const float* __restrict__ H1,
                                                    const float* __restrict__ W2,
                                                    const float* __restrict__ asw,
                                                    const float* __restrict__ adw,
                                                    float* __restrict__ H2p,
                                                    float* __restrict__ as2,
                                                    float* __restrict__ ad2, int Nn) {
    __shared__ float Hs[G2R][HD + 1];
    __shared__ float W2s[HD][NC];
    __shared__ float asv[NC], adv[NC];
    int tid = threadIdx.x;
    for (int i = tid; i < HD * NC; i += 256) W2s[i / NC][i % NC] = W2[i];
    if (tid < NC) { asv[tid] = asw[tid]; adv[tid] = adw[tid]; }
    int row0 = blockIdx.x * G2R;
#pragma unroll
    for (int i = 0; i < 4; ++i) {
        int linear = i * 1024 + tid * 4;
        int r = linear >> 6, c = linear & 63;
        int gr = row0 + r;
        float4 v = make_float4(0.f, 0.f, 0.f, 0.f);
        if (gr < Nn) v = *reinterpret_cast<const float4*>(&H1[(size_t)gr * HD + c]);
        Hs[r][c + 0] = v.x; Hs[r][c + 1] = v.y; Hs[r][c + 2] = v.z; Hs[r][c + 3] = v.w;
    }
    __syncthreads();
    int row = tid >> 2, cg = tid & 3;      // 64 rows x 4 col-groups of 10
    int gr = row0 + row;
    float acc[10];
#pragma unroll
    for (int j = 0; j < 10; ++j) acc[j] = 0.0f;
    for (int k = 0; k < HD; ++k) {
        float a = Hs[row][k];
#pragma unroll
        for (int j = 0; j < 10; ++j) acc[j] += a * W2s[k][cg * 10 + j];
    }
    float sa = 0.0f, da = 0.0f;
#pragma unroll
    for (int j = 0; j < 10; ++j) {
        sa += acc[j] * asv[cg * 10 + j];
        da += acc[j] * adv[cg * 10 + j];
    }
    sa += __shfl_xor(sa, 1); sa += __shfl_xor(sa, 2);
    da += __shfl_xor(da, 1); da += __shfl_xor(da, 2);
    if (gr < Nn) {
        if (cg == 0) { as2[gr] = sa; ad2[gr] = da; }
        float* o = &H2p[(size_t)gr * NC + cg * 10];
#pragma unroll
        for (int j = 0; j < 10; j += 2) {
            *reinterpret_cast<float2*>(&o[j]) = make_float2(acc[j], acc[j + 1]);
        }
    }
}

// ---------------- agg2: fused exp+denom+aggregate + bias + log_softmax -------------
__global__ __launch_bounds__(256) void agg2_kernel(const float* __restrict__ H2p,
                                                   const float* __restrict__ as2,
                                                   const float* __restrict__ ad2,
                                                   const int* __restrict__ col,
                                                   const int* __restrict__ rp,
                                                   const float* __restrict__ b2,
                                                   float* __restrict__ out, int Nn) {
    int n = blockIdx.x * 4 + (threadIdx.x >> 6);
    int lane = threadIdx.x & 63;
    if (n >= Nn) return;
    int slot = lane >> 4, l16 = lane & 15;
    bool act = l16 < 10;
    int beg = rp[n], end = rp[n + 1];
    float adv = ad2[n];
    float4 acc = make_float4(0.f, 0.f, 0.f, 0.f);
    float dw = 0.f;
    for (int t = beg + slot; t < end; t += 4) {
        int s = col[t];
        float w = __expf(lrelu(as2[s] + adv));
        dw += w;
        if (act) {
            float4 v = *reinterpret_cast<const float4*>(&H2p[(size_t)s * NC + l16 * 4]);
            acc.x += w * v.x; acc.y += w * v.y; acc.z += w * v.z; acc.w += w * v.w;
        }
    }
#pragma unroll
    for (int mask = 16; mask < 64; mask <<= 1) {
        acc.x += __shfl_xor(acc.x, mask);
        acc.y += __shfl_xor(acc.y, mask);
        acc.z += __shfl_xor(acc.z, mask);
        acc.w += __shfl_xor(acc.w, mask);
        dw    += __shfl_xor(dw, mask);
    }
    float w = __expf(lrelu(as2[n] + adv));
    dw += w;
    float invd = 1.0f / (dw + 1e-16f);
    if (act) {
        float4 v = *reinterpret_cast<const float4*>(&H2p[(size_t)n * NC + l16 * 4]);
        float4 bb = *reinterpret_cast<const float4*>(&b2[l16 * 4]);
        acc.x = (acc.x + w * v.x) * invd + bb.x;
        acc.y = (acc.y + w * v.y) * invd + bb.y;
        acc.z = (acc.z + w * v.z) * invd + bb.z;
        acc.w = (acc.w + w * v.w) * invd + bb.w;
    }
    float mloc = act ? fmaxf(fmaxf(acc.x, acc.y), fmaxf(acc.z, acc.w)) : -INFINITY;
#pragma unroll
    for (int mask = 1; mask < 16; mask <<= 1) mloc = fmaxf(mloc, __shfl_xor(mloc, mask));
    float s4 = act ? (__expf(acc.x - mloc) + __expf(acc.y - mloc) +
                      __expf(acc.z - mloc) + __expf(acc.w - mloc)) : 0.0f;
#pragma unroll
    for (int mask = 1; mask < 16; mask <<= 1) s4 += __shfl_xor(s4, mask);
    float lse = mloc + __logf(s4);
    if (slot == 0 && act) {
        float4 o = make_float4(acc.x - lse, acc.y - lse, acc.z - lse, acc.w - lse);
        *reinterpret_cast<float4*>(&out[(size_t)n * NC + l16 * 4]) = o;
    }
}

extern "C" void kernel_launch(void* const* d_in, const int* in_sizes, int n_in,
                              void* d_out, int out_size, void* d_ws, size_t ws_size,
                              hipStream_t stream) {
    const float* x    = (const float*)d_in[0];
    const int*   ei   = (const int*)d_in[1];
    const float* W1   = (const float*)d_in[2];
    const float* as1w = (const float*)d_in[3];
    const float* ad1w = (const float*)d_in[4];
    const float* b1   = (const float*)d_in[5];
    const float* W2   = (const float*)d_in[6];
    const float* as2w = (const float*)d_in[7];
    const float* ad2w = (const float*)d_in[8];
    const float* b2   = (const float*)d_in[9];
    float* out = (float*)d_out;

    int Nn = in_sizes[0] / F_IN;
    int E  = in_sizes[1] / 2;
    const int* srcv = ei;
    const int* dstv = ei + E;

    char* ws = (char*)d_ws;
    size_t off = 0;
    auto alloc = [&](size_t bytes) { size_t cur = off; off += (bytes + 255) & ~255ULL; return cur; };
    float* h1p  = (float*)(ws + alloc((size_t)Nn * HD * 4));
    float* h1   = (float*)(ws + alloc((size_t)Nn * HD * 4));
    float* as1v = (float*)(ws + alloc((size_t)Nn * NHEAD * 4));
    float* ad1v = (float*)(ws + alloc((size_t)Nn * NHEAD * 4));
    float* h2p  = (float*)(ws + alloc((size_t)Nn * NC * 4));
    float* as2v = (float*)(ws + alloc((size_t)Nn * 4));
    float* ad2v = (float*)(ws + alloc((size_t)Nn * 4));
    int* deg  = (int*)(ws + alloc((size_t)Nn * 4));
    int* incl = (int*)(ws + alloc((size_t)Nn * 4));
    int* rp   = (int*)(ws + alloc((size_t)(Nn + 1) * 4));
    int* pos  = (int*)(ws + alloc((size_t)E * 4));
    int* col  = (int*)(ws + alloc((size_t)E * 4));
    int* bsum = (int*)(ws + alloc(256 * 4));

    int nb = (Nn + 1023) / 1024;

    hipMemsetAsync(deg, 0, (size_t)Nn * 4, stream);
    count_kernel<<<(E + 255) / 256, 256, 0, stream>>>(dstv, deg, pos, E);
    scanA_kernel<<<nb, 256, 0, stream>>>(deg, incl, bsum, Nn);
    scanB_kernel<<<1, 64, 0, stream>>>(bsum, nb);
    scanC_kernel<<<(Nn + 255) / 256, 256, 0, stream>>>(incl, bsum, rp, Nn);
    scatter_kernel<<<(E + 255) / 256, 256, 0, stream>>>(srcv, dstv, pos, rp, col, E);

    gemm1_kernel<<<(Nn + G1_BM - 1) / G1_BM, 256, 0, stream>>>(x, W1, as1w, ad1w, h1p, as1v, ad1v, Nn);
    agg1_kernel<<<(Nn + 3) / 4, 256, 0, stream>>>(h1p, as1v, ad1v, col, rp, b1, h1, Nn);
    gemm2_kernel<<<(Nn + G2R - 1) / G2R, 256, 0, stream>>>(h1, W2, as2w, ad2w, h2p, as2v, ad2v, Nn);
    agg2_kernel<<<(Nn + 3) / 4, 256, 0, stream>>>(h2p, as2v, ad2v, col, rp, b2, out, Nn);
}

// Round 6
// 383.516 us; speedup vs baseline: 2.4619x; 1.0860x over previous
//
#include <hip/hip_runtime.h>

#define F_IN   512
#define HD     64     // H*D layer-1 output width
#define NHEAD  8
#define NC     40     // classes
#define NEG    0.2f

typedef __attribute__((ext_vector_type(8))) short bf16x8;
typedef __attribute__((ext_vector_type(4))) float f32x4;

__device__ __forceinline__ float lrelu(float x) { return x > 0.0f ? x : NEG * x; }

__device__ __forceinline__ short f2bf(float f) {
    unsigned u = __float_as_uint(f);
    u += 0x7FFF + ((u >> 16) & 1);   // RNE to bf16
    return (short)(u >> 16);
}
__device__ __forceinline__ float bf2f(short h) {
    return __uint_as_float(((unsigned)(unsigned short)h) << 16);
}

// ---------------- CSR build ----------------
__global__ void count_kernel(const int* __restrict__ dst, int* __restrict__ deg,
                             int* __restrict__ pos, int E) {
    int e = blockIdx.x * 256 + threadIdx.x;
    if (e < E) pos[e] = atomicAdd(&deg[dst[e]], 1);
}

__global__ __launch_bounds__(256) void scanA_kernel(const int* __restrict__ deg,
                                                    int* __restrict__ incl,
                                                    int* __restrict__ bsum, int Nn) {
    __shared__ int wsum[4];
    int t = threadIdx.x, b = blockIdx.x;
    int base = b * 1024 + t * 4;
    int v0 = (base + 0) < Nn ? deg[base + 0] : 0;
    int v1 = (base + 1) < Nn ? deg[base + 1] : 0;
    int v2 = (base + 2) < Nn ? deg[base + 2] : 0;
    int v3 = (base + 3) < Nn ? deg[base + 3] : 0;
    int p0 = v0, p1 = p0 + v1, p2 = p1 + v2, p3 = p2 + v3;
    int lane = t & 63, w = t >> 6;
    int sc = p3;
    for (int off = 1; off < 64; off <<= 1) {
        int u = __shfl_up(sc, off);
        if (lane >= off) sc += u;
    }
    if (lane == 63) wsum[w] = sc;
    __syncthreads();
    int woff = 0;
#pragma unroll
    for (int i = 0; i < 4; ++i) if (i < w) woff += wsum[i];
    int excl = woff + sc - p3;
    if (base + 0 < Nn) incl[base + 0] = excl + p0;
    if (base + 1 < Nn) incl[base + 1] = excl + p1;
    if (base + 2 < Nn) incl[base + 2] = excl + p2;
    if (base + 3 < Nn) incl[base + 3] = excl + p3;
    if (t == 0) bsum[b] = wsum[0] + wsum[1] + wsum[2] + wsum[3];
}

__global__ void scanB_kernel(int* __restrict__ bsum, int nb) {
    int lane = threadIdx.x;  // 64 threads
    int a = lane < nb ? bsum[lane] : 0;
    int c = (lane + 64) < nb ? bsum[lane + 64] : 0;
    int sa = a, sc2 = c;
    for (int off = 1; off < 64; off <<= 1) {
        int u = __shfl_up(sa, off);  if (lane >= off) sa += u;
        int u2 = __shfl_up(sc2, off); if (lane >= off) sc2 += u2;
    }
    int totA = __shfl(sa, 63);
    int ea = sa - a;
    int ec = totA + sc2 - c;
    if (lane < nb) bsum[lane] = ea;
    if (lane + 64 < nb) bsum[lane + 64] = ec;
}

__global__ void scanC_kernel(const int* __restrict__ incl, const int* __restrict__ bsum,
                             int* __restrict__ rp, int Nn) {
    int i = blockIdx.x * 256 + threadIdx.x;
    if (i == 0) rp[0] = 0;
    if (i < Nn) rp[i + 1] = incl[i] + bsum[i >> 10];
}

__global__ void scatter_kernel(const int* __restrict__ src, const int* __restrict__ dst,
                               const int* __restrict__ pos, const int* __restrict__ rp,
                               int* __restrict__ col, int E) {
    int e = blockIdx.x * 256 + threadIdx.x;
    if (e < E) {
        int d = dst[e];
        int p = rp[d] + pos[e];
        __builtin_nontemporal_store(src[e], &col[p]);
    }
}

// ---------------- GEMM1 (MFMA): h1p = x @ W1, fused alpha1 epilogue ----------
// A (x) loaded DIRECTLY from global into fragments (row=lane&15, k=(lane>>4)*8+j),
// converted to bf16 in-register (X lo-part dropped: error ~6e-4, safe).
// W split hi+lo, staged in LDS layout B[kgrp][col][8] -> conflict-free b128 R/W.
// acc += a_h*(w_h) + a_h*(w_l) : 2 MFMA per acc per K-step.
#define G1_BM 128
__global__ __launch_bounds__(256) void gemm1_kernel(const float* __restrict__ X,
                                                    const float* __restrict__ W,
                                                    const float* __restrict__ att_s,
                                                    const float* __restrict__ att_d,
                                                    float* __restrict__ Hout,
                                                    float* __restrict__ as1,
                                                    float* __restrict__ ad1, int Nn) {
    __shared__ short Bh[4][HD][8];   // [kgrp][col][kk&7]
    __shared__ short Bl[4][HD][8];
    int tid = threadIdx.x;
    int wid = tid >> 6, lane = tid & 63;
    int lrow = lane & 15, kgrp = lane >> 4;
    int row0 = blockIdx.x * G1_BM;
    int rowA = row0 + wid * 32 + lrow;   // fr adds 16

    int sc = tid & 63, skc = tid >> 6;   // B staging: col, k-chunk

    float ats[4], atd[4];
#pragma unroll
    for (int fc = 0; fc < 4; ++fc) { ats[fc] = att_s[fc * 16 + lrow]; atd[fc] = att_d[fc * 16 + lrow]; }

    f32x4 acc[2][4];
#pragma unroll
    for (int fr = 0; fr < 2; ++fr)
#pragma unroll
        for (int fc = 0; fc < 4; ++fc) acc[fr][fc] = (f32x4){0.f, 0.f, 0.f, 0.f};

    float4 a_cur[2][2], a_nxt[2][2];
    // prologue: load A for it=0
#pragma unroll
    for (int fr = 0; fr < 2; ++fr) {
        int gr = rowA + fr * 16;
        if (gr < Nn) {
            const float* p = X + (size_t)gr * F_IN + kgrp * 8;
            a_cur[fr][0] = *reinterpret_cast<const float4*>(p);
            a_cur[fr][1] = *reinterpret_cast<const float4*>(p + 4);
        } else {
            a_cur[fr][0] = a_cur[fr][1] = make_float4(0.f, 0.f, 0.f, 0.f);
        }
    }

    for (int it = 0; it < F_IN / 32; ++it) {
        int k0 = it * 32;
        // issue W loads for this iter (consumed after sync1)
        float wreg[8];
#pragma unroll
        for (int j = 0; j < 8; ++j)
            wreg[j] = W[(size_t)(k0 + skc * 8 + j) * HD + sc];
        // issue next-iter A loads (consumed next iter)
        if (it + 1 < F_IN / 32) {
#pragma unroll
            for (int fr = 0; fr < 2; ++fr) {
                int gr = rowA + fr * 16;
                if (gr < Nn) {
                    const float* p = X + (size_t)gr * F_IN + (k0 + 32) + kgrp * 8;
                    a_nxt[fr][0] = *reinterpret_cast<const float4*>(p);
                    a_nxt[fr][1] = *reinterpret_cast<const float4*>(p + 4);
                } else {
                    a_nxt[fr][0] = a_nxt[fr][1] = make_float4(0.f, 0.f, 0.f, 0.f);
                }
            }
        }
        // convert current A to bf16 fragments (VALU, overlaps loads)
        bf16x8 af[2];
#pragma unroll
        for (int fr = 0; fr < 2; ++fr) {
            float fs[8] = {a_cur[fr][0].x, a_cur[fr][0].y, a_cur[fr][0].z, a_cur[fr][0].w,
                           a_cur[fr][1].x, a_cur[fr][1].y, a_cur[fr][1].z, a_cur[fr][1].w};
#pragma unroll
            for (int j = 0; j < 8; ++j) af[fr][j] = f2bf(fs[j]);
        }
        __syncthreads();   // all waves done reading previous B tile
        {
            bf16x8 vh, vl;
#pragma unroll
            for (int j = 0; j < 8; ++j) {
                short hh = f2bf(wreg[j]);
                vh[j] = hh;
                vl[j] = f2bf(wreg[j] - bf2f(hh));
            }
            *reinterpret_cast<bf16x8*>(&Bh[skc][sc][0]) = vh;
            *reinterpret_cast<bf16x8*>(&Bl[skc][sc][0]) = vl;
        }
        __syncthreads();   // B tile ready
        bf16x8 bh[4], bl[4];
#pragma unroll
        for (int fc = 0; fc < 4; ++fc) {
            bh[fc] = *reinterpret_cast<const bf16x8*>(&Bh[kgrp][fc * 16 + lrow][0]);
            bl[fc] = *reinterpret_cast<const bf16x8*>(&Bl[kgrp][fc * 16 + lrow][0]);
        }
#pragma unroll
        for (int fr = 0; fr < 2; ++fr)
#pragma unroll
            for (int fc = 0; fc < 4; ++fc) {
                acc[fr][fc] = __builtin_amdgcn_mfma_f32_16x16x32_bf16(af[fr], bh[fc], acc[fr][fc], 0, 0, 0);
                acc[fr][fc] = __builtin_amdgcn_mfma_f32_16x16x32_bf16(af[fr], bl[fc], acc[fr][fc], 0, 0, 0);
            }
        if (it + 1 < F_IN / 32) {
#pragma unroll
            for (int fr = 0; fr < 2; ++fr) {
                a_cur[fr][0] = a_nxt[fr][0];
                a_cur[fr][1] = a_nxt[fr][1];
            }
        }
    }

    // epilogue: store h + fused per-head attention logits
#pragma unroll
    for (int fr = 0; fr < 2; ++fr) {
#pragma unroll
        for (int r = 0; r < 4; ++r) {
            int gr = row0 + wid * 32 + fr * 16 + kgrp * 4 + r;
            float hv[4], sp[4], dp[4];
#pragma unroll
            for (int fc = 0; fc < 4; ++fc) {
                hv[fc] = acc[fr][fc][r];
                sp[fc] = hv[fc] * ats[fc];
                dp[fc] = hv[fc] * atd[fc];
            }
#pragma unroll
            for (int mask = 1; mask <= 4; mask <<= 1) {
#pragma unroll
                for (int fc = 0; fc < 4; ++fc) {
                    sp[fc] += __shfl_xor(sp[fc], mask);
                    dp[fc] += __shfl_xor(dp[fc], mask);
                }
            }
            if (gr < Nn) {
#pragma unroll
                for (int fc = 0; fc < 4; ++fc)
                    Hout[(size_t)gr * HD + fc * 16 + lrow] = hv[fc];
                if ((lane & 7) == 0) {
                    int hh = lrow >> 3;
#pragma unroll
                    for (int fc = 0; fc < 4; ++fc) {
                        as1[gr * NHEAD + fc * 2 + hh] = sp[fc];
                        ad1[gr * NHEAD + fc * 2 + hh] = dp[fc];
                    }
                }
            }
        }
    }
}

// ---------------- agg1: fused exp+denom+aggregate (no max pass) + bias + ELU -------
__global__ __launch_bounds__(256) void agg1_kernel(const float* __restrict__ Hp,
                                                   const float* __restrict__ as1,
                                                   const float* __restrict__ ad1,
                                                   const int* __restrict__ col,
                                                   const int* __restrict__ rp,
                                                   const float* __restrict__ b1,
                                                   float* __restrict__ H1out, int Nn) {
    int n = blockIdx.x * 4 + (threadIdx.x >> 6);
    int lane = threadIdx.x & 63;
    if (n >= Nn) return;
    int slot = lane >> 4, l16 = lane & 15, h = l16 >> 1;
    int beg = rp[n], end = rp[n + 1];
    float adv = ad1[n * NHEAD + h];
    float4 acc = make_float4(0.f, 0.f, 0.f, 0.f);
    float dw = 0.f;
    for (int t = beg + slot; t < end; t += 4) {
        int s = col[t];
        float w = __expf(lrelu(as1[s * NHEAD + h] + adv));
        dw += w;
        float4 v = *reinterpret_cast<const float4*>(&Hp[(size_t)s * HD + l16 * 4]);
        acc.x += w * v.x; acc.y += w * v.y; acc.z += w * v.z; acc.w += w * v.w;
    }
#pragma unroll
    for (int mask = 16; mask < 64; mask <<= 1) {
        acc.x += __shfl_xor(acc.x, mask);
        acc.y += __shfl_xor(acc.y, mask);
        acc.z += __shfl_xor(acc.z, mask);
        acc.w += __shfl_xor(acc.w, mask);
        dw    += __shfl_xor(dw, mask);
    }
    if (slot == 0) {
        float w = __expf(lrelu(as1[n * NHEAD + h] + adv));
        float4 v = *reinterpret_cast<const float4*>(&Hp[(size_t)n * HD + l16 * 4]);
        acc.x += w * v.x; acc.y += w * v.y; acc.z += w * v.z; acc.w += w * v.w;
        dw += w;
        float invd = 1.0f / (dw + 1e-16f);
        float4 bb = *reinterpret_cast<const float4*>(&b1[l16 * 4]);
        acc.x = acc.x * invd + bb.x; acc.y = acc.y * invd + bb.y;
        acc.z = acc.z * invd + bb.z; acc.w = acc.w * invd + bb.w;
        acc.x = acc.x > 0.0f ? acc.x : __expf(acc.x) - 1.0f;
        acc.y = acc.y > 0.0f ? acc.y : __expf(acc.y) - 1.0f;
        acc.z = acc.z > 0.0f ? acc.z : __expf(acc.z) - 1.0f;
        acc.w = acc.w > 0.0f ? acc.w : __expf(acc.w) - 1.0f;
        *reinterpret_cast<float4*>(&H1out[(size_t)n * HD + l16 * 4]) = acc;
    }
}

// ---------------- GEMM2: tiled (64 rows/block) + fused alpha2 ----------------
#define G2R 64
__global__ __launch_bounds__(256) void gemm2_kernel(const float* __restrict__ H1,
                                                    const float* __restrict__ W2,
                                                    const float* __restrict__ asw,
                                                    const float* __restrict__ adw,
                                                    float* __restrict__ H2p,
                                                    float* __restrict__ as2,
                                                    float* __restrict__ ad2, int Nn) {
    __shared__ float Hs[G2R][HD + 1];
    __shared__ float W2s[HD][NC];
    __shared__ float asv[NC], adv[NC];
    int tid = threadIdx.x;
    for (int i = tid; i < HD * NC; i += 256) W2s[i / NC][i % NC] = W2[i];
    if (tid < NC) { asv[tid] = asw[tid]; adv[tid] = adw[tid]; }
    int row0 = blockIdx.x * G2R;
#pragma unroll
    for (int i = 0; i < 4; ++i) {
        int linear = i * 1024 + tid * 4;
        int r = linear >> 6, c = linear & 63;
        int gr = row0 + r;
        float4 v = make_float4(0.f, 0.f, 0.f, 0.f);
        if (gr < Nn) v = *reinterpret_cast<const float4*>(&H1[(size_t)gr * HD + c]);
        Hs[r][c + 0] = v.x; Hs[r][c + 1] = v.y; Hs[r][c + 2] = v.z; Hs[r][c + 3] = v.w;
    }
    __syncthreads();
    int row = tid >> 2, cg = tid & 3;      // 64 rows x 4 col-groups of 10
    int gr = row0 + row;
    float acc[10];
#pragma unroll
    for (int j = 0; j < 10; ++j) acc[j] = 0.0f;
    for (int k = 0; k < HD; ++k) {
        float a = Hs[row][k];
#pragma unroll
        for (int j = 0; j < 10; ++j) acc[j] += a * W2s[k][cg * 10 + j];
    }
    float sa = 0.0f, da = 0.0f;
#pragma unroll
    for (int j = 0; j < 10; ++j) {
        sa += acc[j] * asv[cg * 10 + j];
        da += acc[j] * adv[cg * 10 + j];
    }
    sa += __shfl_xor(sa, 1); sa += __shfl_xor(sa, 2);
    da += __shfl_xor(da, 1); da += __shfl_xor(da, 2);
    if (gr < Nn) {
        if (cg == 0) { as2[gr] = sa; ad2[gr] = da; }
        float* o = &H2p[(size_t)gr * NC + cg * 10];
#pragma unroll
        for (int j = 0; j < 10; j += 2) {
            *reinterpret_cast<float2*>(&o[j]) = make_float2(acc[j], acc[j + 1]);
        }
    }
}

// ---------------- agg2: fused exp+denom+aggregate + bias + log_softmax -------------
__global__ __launch_bounds__(256) void agg2_kernel(const float* __restrict__ H2p,
                                                   const float* __restrict__ as2,
                                                   const float* __restrict__ ad2,
                                                   const int* __restrict__ col,
                                                   const int* __restrict__ rp,
                                                   const float* __restrict__ b2,
                                                   float* __restrict__ out, int Nn) {
    int n = blockIdx.x * 4 + (threadIdx.x >> 6);
    int lane = threadIdx.x & 63;
    if (n >= Nn) return;
    int slot = lane >> 4, l16 = lane & 15;
    bool act = l16 < 10;
    int beg = rp[n], end = rp[n + 1];
    float adv = ad2[n];
    float4 acc = make_float4(0.f, 0.f, 0.f, 0.f);
    float dw = 0.f;
    for (int t = beg + slot; t < end; t += 4) {
        int s = col[t];
        float w = __expf(lrelu(as2[s] + adv));
        dw += w;
        if (act) {
            float4 v = *reinterpret_cast<const float4*>(&H2p[(size_t)s * NC + l16 * 4]);
            acc.x += w * v.x; acc.y += w * v.y; acc.z += w * v.z; acc.w += w * v.w;
        }
    }
#pragma unroll
    for (int mask = 16; mask < 64; mask <<= 1) {
        acc.x += __shfl_xor(acc.x, mask);
        acc.y += __shfl_xor(acc.y, mask);
        acc.z += __shfl_xor(acc.z, mask);
        acc.w += __shfl_xor(acc.w, mask);
        dw    += __shfl_xor(dw, mask);
    }
    float w = __expf(lrelu(as2[n] + adv));
    dw += w;
    float invd = 1.0f / (dw + 1e-16f);
    if (act) {
        float4 v = *reinterpret_cast<const float4*>(&H2p[(size_t)n * NC + l16 * 4]);
        float4 bb = *reinterpret_cast<const float4*>(&b2[l16 * 4]);
        acc.x = (acc.x + w * v.x) * invd + bb.x;
        acc.y = (acc.y + w * v.y) * invd + bb.y;
        acc.z = (acc.z + w * v.z) * invd + bb.z;
        acc.w = (acc.w + w * v.w) * invd + bb.w;
    }
    float mloc = act ? fmaxf(fmaxf(acc.x, acc.y), fmaxf(acc.z, acc.w)) : -INFINITY;
#pragma unroll
    for (int mask = 1; mask < 16; mask <<= 1) mloc = fmaxf(mloc, __shfl_xor(mloc, mask));
    float s4 = act ? (__expf(acc.x - mloc) + __expf(acc.y - mloc) +
                      __expf(acc.z - mloc) + __expf(acc.w - mloc)) : 0.0f;
#pragma unroll
    for (int mask = 1; mask < 16; mask <<= 1) s4 += __shfl_xor(s4, mask);
    float lse = mloc + __logf(s4);
    if (slot == 0 && act) {
        float4 o = make_float4(acc.x - lse, acc.y - lse, acc.z - lse, acc.w - lse);
        *reinterpret_cast<float4*>(&out[(size_t)n * NC + l16 * 4]) = o;
    }
}

extern "C" void kernel_launch(void* const* d_in, const int* in_sizes, int n_in,
                              void* d_out, int out_size, void* d_ws, size_t ws_size,
                              hipStream_t stream) {
    const float* x    = (const float*)d_in[0];
    const int*   ei   = (const int*)d_in[1];
    const float* W1   = (const float*)d_in[2];
    const float* as1w = (const float*)d_in[3];
    const float* ad1w = (const float*)d_in[4];
    const float* b1   = (const float*)d_in[5];
    const float* W2   = (const float*)d_in[6];
    const float* as2w = (const float*)d_in[7];
    const float* ad2w = (const float*)d_in[8];
    const float* b2   = (const float*)d_in[9];
    float* out = (float*)d_out;

    int Nn = in_sizes[0] / F_IN;
    int E  = in_sizes[1] / 2;
    const int* srcv = ei;
    const int* dstv = ei + E;

    char* ws = (char*)d_ws;
    size_t off = 0;
    auto alloc = [&](size_t bytes) { size_t cur = off; off += (bytes + 255) & ~255ULL; return cur; };
    float* h1p  = (float*)(ws + alloc((size_t)Nn * HD * 4));
    float* h1   = (float*)(ws + alloc((size_t)Nn * HD * 4));
    float* as1v = (float*)(ws + alloc((size_t)Nn * NHEAD * 4));
    float* ad1v = (float*)(ws + alloc((size_t)Nn * NHEAD * 4));
    float* h2p  = (float*)(ws + alloc((size_t)Nn * NC * 4));
    float* as2v = (float*)(ws + alloc((size_t)Nn * 4));
    float* ad2v = (float*)(ws + alloc((size_t)Nn * 4));
    int* deg  = (int*)(ws + alloc((size_t)Nn * 4));
    int* incl = (int*)(ws + alloc((size_t)Nn * 4));
    int* rp   = (int*)(ws + alloc((size_t)(Nn + 1) * 4));
    int* pos  = (int*)(ws + alloc((size_t)E * 4));
    int* col  = (int*)(ws + alloc((size_t)E * 4));
    int* bsum = (int*)(ws + alloc(256 * 4));

    int nb = (Nn + 1023) / 1024;

    hipMemsetAsync(deg, 0, (size_t)Nn * 4, stream);
    count_kernel<<<(E + 255) / 256, 256, 0, stream>>>(dstv, deg, pos, E);
    scanA_kernel<<<nb, 256, 0, stream>>>(deg, incl, bsum, Nn);
    scanB_kernel<<<1, 64, 0, stream>>>(bsum, nb);
    scanC_kernel<<<(Nn + 255) / 256, 256, 0, stream>>>(incl, bsum, rp, Nn);
    scatter_kernel<<<(E + 255) / 256, 256, 0, stream>>>(srcv, dstv, pos, rp, col, E);

    gemm1_kernel<<<(Nn + G1_BM - 1) / G1_BM, 256, 0, stream>>>(x, W1, as1w, ad1w, h1p, as1v, ad1v, Nn);
    agg1_kernel<<<(Nn + 3) / 4, 256, 0, stream>>>(h1p, as1v, ad1v, col, rp, b1, h1, Nn);
    gemm2_kernel<<<(Nn + G2R - 1) / G2R, 256, 0, stream>>>(h1, W2, as2w, ad2w, h2p, as2v, ad2v, Nn);
    agg2_kernel<<<(Nn + 3) / 4, 256, 0, stream>>>(h2p, as2v, ad2v, col, rp, b2, out, Nn);
}